// Round 16
// baseline (690.328 us; speedup 1.0000x reference)
//
#include <hip/hip_runtime.h>
#include <hip/hip_bf16.h>
#include <math.h>

// ----------------------------------------------------------------------------
// vMFLunaBlock v16: v15 with bgemm deepened to a 4-buffer ring: stage t+3,
// wait vmcnt(8) (2 tiles / ~600cy of slack > HBM latency). BM=128 everywhere
// (64KB LDS -> 2 blocks/CU, independent barrier groups). Attns/conv/LN as v15.
// Workspace: 40,894,464 floats = 163.6 MB (same audited regions).
// ----------------------------------------------------------------------------

typedef unsigned short u16;
typedef __attribute__((ext_vector_type(8))) short bf8v;
typedef __attribute__((ext_vector_type(4))) float f4v;
typedef __attribute__((ext_vector_type(4))) unsigned short us4v;

#define AS1 __attribute__((address_space(1)))
#define AS3 __attribute__((address_space(3)))

__device__ __forceinline__ void gld_lds16(const void* g, void* l) {
  __builtin_amdgcn_global_load_lds((const AS1 unsigned int*)g,
                                   (AS3 unsigned int*)l, 16, 0, 0);
}

__device__ __forceinline__ u16 bf16_rne(float x) {
  unsigned u = __float_as_uint(x);
  return (u16)((u + 0x7fffu + ((u >> 16) & 1u)) >> 16);
}
__device__ __forceinline__ float bf16_to_f(u16 h) {
  return __uint_as_float(((unsigned)h) << 16);
}

// ---------------- batched fp32 -> bf16 convert (up to 8 segments) -----------
struct Cvt8 {
  const float* src[8];
  u16* dst[8];
  int n4[8];
  float sc[8];
  int cum[9];
  int ns;
};
__global__ __launch_bounds__(256) void tobf16_multi_kernel(Cvt8 c) {
  int b = blockIdx.x;
  int seg = 0;
  while (seg + 1 < c.ns && b >= c.cum[seg + 1]) ++seg;
  int i = (b - c.cum[seg]) * 256 + threadIdx.x;
  if (i >= c.n4[seg]) return;
  const float sc = c.sc[seg];
  float4 v = ((const float4*)c.src[seg])[i];
  us4v h;
  h[0] = bf16_rne(v.x * sc); h[1] = bf16_rne(v.y * sc);
  h[2] = bf16_rne(v.z * sc); h[3] = bf16_rne(v.w * sc);
  ((us4v*)c.dst[seg])[i] = h;
}

// ---------------- bf16 MFMA GEMM, 4-buffer deep-prefetch pipeline -----------
// C = scale*(A @ B^T) [+GELU]. OMODE: 0=fp32, 1=bf16, 2=both.
// Tile 128x128, BK=32, 4 waves (2x2), wave tile 64x64. Per-wave loads/tile
// VW=4 (2 A + 2 B). Ring of 4 LDS buffers; stage tile t+3; wait vmcnt(8)
// leaves tiles t+2,t+3 in flight (tile t+1 is ~2 iters old -> latency covered).
// Requires K >= 128 (NT >= 4); all call sites have K in {768,3072}.
template <int GELU, int OMODE>
__global__ __launch_bounds__(256) void bgemm_kernel(
    const u16* __restrict__ A, const u16* __restrict__ B,
    float* __restrict__ Cf, u16* __restrict__ Cb, int M, int N, int K,
    int lda, int ldb, int ldc, long long aSB, long long aSH, long long bSB,
    long long bSH, long long cSB, long long cSH, int HB, float scale) {
  __shared__ u16 smA[4][4096];
  __shared__ u16 smB[4][4096];
  const int t = threadIdx.x;
  const int w = t >> 6, lane = t & 63;
  const int z = blockIdx.z;
  const int bb = z / HB, hh = z % HB;
  const u16* Ab = A + bb * aSB + hh * aSH;
  const u16* Bb = B + bb * bSB + hh * bSH;
  float* Cfb = (OMODE != 1) ? (Cf + bb * cSB + hh * cSH) : nullptr;
  u16* Cbb = (OMODE >= 1) ? (Cb + bb * cSB + hh * cSH) : nullptr;

  const int gx = gridDim.x;
  const int nwg = gx * gridDim.y;
  int f = blockIdx.x + gx * blockIdx.y;
  if ((nwg & 7) == 0) {
    const int cpx = nwg >> 3;
    f = (f & 7) * cpx + (f >> 3);
  }
  const int row0 = (f / gx) * 128, col0 = (f % gx) * 128;

  const int brow_l = lane >> 2;
  const int bchunk = ((lane & 3) ^ ((lane >> 3) & 3)) * 8;
  const int fr = lane & 15;
  const int fq = lane >> 4;
  const int fco = (fq ^ ((lane >> 1) & 3)) * 8;
  const int wr = (w >> 1) * 64, wc = (w & 1) * 64;

  f4v acc[4][4];
#pragma unroll
  for (int i = 0; i < 4; ++i)
#pragma unroll
    for (int j = 0; j < 4; ++j) acc[i][j] = {0.f, 0.f, 0.f, 0.f};

  const int NT = K >> 5;

  auto stage = [&](int tile, int buf) {
    const int k0 = tile << 5;
#pragma unroll
    for (int i = 0; i < 2; ++i) {  // A: 8 groups over 4 waves
      const int g = w * 2 + i;
      const int r = g * 16 + brow_l;
      gld_lds16(Ab + (long long)(row0 + r) * lda + k0 + bchunk,
                &smA[buf][g * 512 + lane * 8]);
    }
#pragma unroll
    for (int i = 0; i < 2; ++i) {  // B: 8 groups over 4 waves
      const int g = w * 2 + i;
      const int r = g * 16 + brow_l;
      gld_lds16(Bb + (long long)(col0 + r) * ldb + k0 + bchunk,
                &smB[buf][g * 512 + lane * 8]);
    }
  };

  // ---- prologue: tiles 0,1,2 in flight; wait tile 0 only (NT >= 4) ----
  stage(0, 0);
  stage(1, 1);
  stage(2, 2);
  asm volatile("s_waitcnt vmcnt(8)" ::: "memory");
  __builtin_amdgcn_sched_barrier(0);
  __builtin_amdgcn_s_barrier();

  for (int tt = 0; tt < NT; ++tt) {
    const int cur = tt & 3;
    if (tt + 3 < NT) stage(tt + 3, (tt + 3) & 3);
    {
      bf8v af[4], bfr[4];
#pragma unroll
      for (int mi = 0; mi < 4; ++mi)
        af[mi] = *(const bf8v*)&smA[cur][(wr + mi * 16 + fr) * 32 + fco];
#pragma unroll
      for (int nj = 0; nj < 4; ++nj)
        bfr[nj] = *(const bf8v*)&smB[cur][(wc + nj * 16 + fr) * 32 + fco];
      __builtin_amdgcn_s_setprio(1);
#pragma unroll
      for (int mi = 0; mi < 4; ++mi)
#pragma unroll
        for (int nj = 0; nj < 4; ++nj)
          acc[mi][nj] = __builtin_amdgcn_mfma_f32_16x16x32_bf16(
              af[mi], bfr[nj], acc[mi][nj], 0, 0, 0);
      __builtin_amdgcn_s_setprio(0);
    }
    // leave tiles {tt+2, tt+3} ∩ [0,NT) in flight; tt+1 must be landed
    if (tt + 3 < NT) {
      asm volatile("s_waitcnt vmcnt(8)" ::: "memory");
    } else if (tt + 2 < NT) {
      asm volatile("s_waitcnt vmcnt(4)" ::: "memory");
    } else if (tt + 1 < NT) {
      asm volatile("s_waitcnt vmcnt(0)" ::: "memory");
    }
    __builtin_amdgcn_sched_barrier(0);
    __builtin_amdgcn_s_barrier();
  }

#pragma unroll
  for (int mi = 0; mi < 4; ++mi)
#pragma unroll
    for (int nj = 0; nj < 4; ++nj) {
      const int col = col0 + wc + nj * 16 + fr;
      const long long base =
          (long long)(row0 + wr + mi * 16 + fq * 4) * ldc + col;
#pragma unroll
      for (int j = 0; j < 4; ++j) {
        float v = acc[mi][nj][j] * scale;
        if (GELU) v = 0.5f * v * (1.f + erff(v * 0.70710678118654752f));
        const long long idx = base + (long long)j * ldc;
        if (OMODE != 1) Cfb[idx] = v;
        if (OMODE >= 1) Cbb[idx] = bf16_rne(v);
      }
    }
}

// ---------------- fused PACK attention (online softmax, exp2 domain) -------
__global__ __launch_bounds__(512) void fused_pack_attn(
    const u16* __restrict__ q, const u16* __restrict__ k,
    const u16* __restrict__ vt, u16* __restrict__ o) {
  __shared__ char pool[110080];
  u16* smQ = (u16*)pool;
  u16* smK = (u16*)(pool + 16384);
  u16* Pbuf = (u16*)(pool + 32768);
  u16* smV = (u16*)(pool + 98304);
  float* partial = (float*)(pool + 106496);
  float* mold = (float*)(pool + 108544);
  float* fbuf = (float*)(pool + 109056);
  float* srow = (float*)(pool + 109568);

  const int t = threadIdx.x;
  const int w = t >> 6, lane = t & 63;
  const int z = blockIdx.z;
  const int b = z / 12, h = z % 12;
  const int qrow0 = b * 256 + blockIdx.x * 128;
  const long long kvbase = ((long long)(b * 12 + h)) * 65536;

  const int fr = lane & 15, fq = lane >> 4;
  const int fco = (fq ^ ((lane >> 1) & 3)) * 8;
  const int brow_l = lane >> 2;
  const int bchunk = ((lane & 3) ^ ((lane >> 3) & 3)) * 8;
  const int wr = (w >> 2) * 64, wc = (w & 3) * 64;
  const int wrp = (w >> 1) * 32, wcp = (w & 1) * 32;

#pragma unroll
  for (int i = 0; i < 2; ++i) {
    const int g = w * 2 + i;
    const int plane = g >> 3, grp = g & 7;
    gld_lds16(q + (long long)(qrow0 + grp * 16 + brow_l) * 768 + h * 64 +
                  plane * 32 + bchunk,
              smQ + plane * 4096 + grp * 512 + lane * 8);
  }
  if (t < 128) {
    mold[t] = -3.0e38f;
    srow[t] = 0.f;
  }

  f4v acc2[2][2];
#pragma unroll
  for (int i = 0; i < 2; ++i)
#pragma unroll
    for (int j = 0; j < 2; ++j) acc2[i][j] = {0.f, 0.f, 0.f, 0.f};

  for (int kc = 0; kc < 4; ++kc) {
    f4v acc[4][4];
#pragma unroll
    for (int i = 0; i < 4; ++i)
#pragma unroll
      for (int j = 0; j < 4; ++j) acc[i][j] = {0.f, 0.f, 0.f, 0.f};

#pragma unroll
    for (int khalf = 0; khalf < 2; ++khalf) {
      __syncthreads();
#pragma unroll
      for (int i = 0; i < 2; ++i) {
        const int g = w * 2 + i;
        gld_lds16(k + kvbase +
                      (long long)(kc * 256 + g * 16 + brow_l) * 64 +
                      khalf * 32 + bchunk,
                  smK + g * 512 + lane * 8);
      }
      __syncthreads();
#pragma unroll
      for (int mi = 0; mi < 4; ++mi) {
        const bf8v a0 =
            *(const bf8v*)&smQ[khalf * 4096 + (wr + mi * 16 + fr) * 32 + fco];
#pragma unroll
        for (int nj = 0; nj < 4; ++nj) {
          const bf8v b0 = *(const bf8v*)&smK[(wc + nj * 16 + fr) * 32 + fco];
          acc[mi][nj] =
              __builtin_amdgcn_mfma_f32_16x16x32_bf16(a0, b0, acc[mi][nj], 0, 0, 0);
        }
      }
    }
    __syncthreads();

#pragma unroll
    for (int mi = 0; mi < 4; ++mi)
#pragma unroll
      for (int j = 0; j < 4; ++j) {
        float m = fmaxf(fmaxf(acc[mi][0][j], acc[mi][1][j]),
                        fmaxf(acc[mi][2][j], acc[mi][3][j]));
#pragma unroll
        for (int o2 = 1; o2 < 16; o2 <<= 1) m = fmaxf(m, __shfl_xor(m, o2));
        if (fr == 0) partial[(w & 3) * 128 + wr + mi * 16 + fq * 4 + j] = m;
      }
    __syncthreads();
    if (t < 128) {
      const float cm = fmaxf(fmaxf(partial[t], partial[128 + t]),
                             fmaxf(partial[256 + t], partial[384 + t]));
      const float mnew = fmaxf(mold[t], cm);
      fbuf[t] = exp2f(mold[t] - mnew);
      mold[t] = mnew;
    }
    __syncthreads();

#pragma unroll
    for (int mi = 0; mi < 4; ++mi)
#pragma unroll
      for (int j = 0; j < 4; ++j) {
        const int row = wr + mi * 16 + fq * 4 + j;
        const float rm = mold[row];
        float s = 0.f;
#pragma unroll
        for (int nj = 0; nj < 4; ++nj) {
          const float e = exp2f(acc[mi][nj][j] - rm);
          s += e;
          const int col = wc + nj * 16 + fr;
          const int kc2 = col >> 5, kloc = col & 31;
          Pbuf[kc2 * 4096 + row * 32 + (((kloc >> 3) ^ ((row >> 1) & 3)) * 8) +
               (kloc & 7)] = bf16_rne(e);
        }
#pragma unroll
        for (int o2 = 1; o2 < 16; o2 <<= 1) s += __shfl_xor(s, o2);
        if (fr == 0) partial[(w & 3) * 128 + row] = s;
      }
    if (w < 4) {
      gld_lds16(vt + kvbase + (long long)(w * 16 + brow_l) * 1024 + kc * 256 +
                    bchunk,
                smV + w * 512 + lane * 8);
    }
    __syncthreads();
    if (t < 128)
      srow[t] = srow[t] * fbuf[t] +
                ((partial[t] + partial[128 + t]) +
                 (partial[256 + t] + partial[384 + t]));
    __syncthreads();

#pragma unroll
    for (int mi = 0; mi < 2; ++mi)
#pragma unroll
      for (int j = 0; j < 4; ++j) {
        const float fr_ = fbuf[wrp + mi * 16 + fq * 4 + j];
        acc2[mi][0][j] *= fr_;
        acc2[mi][1][j] *= fr_;
      }

    for (int sk = 0; sk < 8; ++sk) {
      const int cur = (sk & 1) * 2048;
      if (sk < 7 && w < 4) {
        gld_lds16(vt + kvbase + (long long)(w * 16 + brow_l) * 1024 +
                      kc * 256 + (sk + 1) * 32 + bchunk,
                  smV + (2048 - cur) + w * 512 + lane * 8);
      }
#pragma unroll
      for (int mi = 0; mi < 2; ++mi) {
        const bf8v pa =
            *(const bf8v*)&Pbuf[sk * 4096 + (wrp + mi * 16 + fr) * 32 + fco];
#pragma unroll
        for (int nj = 0; nj < 2; ++nj) {
          const bf8v v0 =
              *(const bf8v*)&smV[cur + (wcp + nj * 16 + fr) * 32 + fco];
          acc2[mi][nj] =
              __builtin_amdgcn_mfma_f32_16x16x32_bf16(pa, v0, acc2[mi][nj], 0, 0, 0);
        }
      }
      __syncthreads();
    }
  }

  if (t < 128) fbuf[t] = 1.f / srow[t];
  __syncthreads();
  const long long ooff = (long long)qrow0 * 768 + h * 64;
#pragma unroll
  for (int mi = 0; mi < 2; ++mi)
#pragma unroll
    for (int nj = 0; nj < 2; ++nj)
#pragma unroll
      for (int j = 0; j < 4; ++j) {
        const int row = wrp + mi * 16 + fq * 4 + j;
        const int col = wcp + nj * 16 + fr;
        o[ooff + (long long)row * 768 + col] =
            bf16_rne(acc2[mi][nj][j] * fbuf[row]);
      }
}

// ---------------- fused unpack attention (bf16, strided q/k) ----------------
__global__ __launch_bounds__(512) void fused_unpack_attn(
    const u16* __restrict__ q, int ldq, const u16* __restrict__ k, int ldk,
    const u16* __restrict__ vt, u16* __restrict__ o) {
  __shared__ char pool[76800];
  u16* smA = (u16*)pool;
  u16* smB = (u16*)(pool + 8192);
  u16* Pbuf = (u16*)pool;
  u16* smV = (u16*)(pool + 65536);
  float* partial = (float*)(pool + 73728);
  float* rowmax = (float*)(pool + 75776);
  float* rowsum = (float*)(pool + 76288);

  const int t = threadIdx.x;
  const int w = t >> 6, lane = t & 63;
  const int z = blockIdx.z;
  const int b = z / 12, h = z % 12;
  const int q0 = blockIdx.x * 128;

  const long long qoff = (long long)(b * 4096 + q0) * ldq + h * 64;
  const long long koff = (long long)(b * 256) * ldk + h * 64;
  const long long vbase = ((long long)(b * 12 + h)) * 16384;
  const long long ooff = (long long)(b * 4096 + q0) * 768 + h * 64;

  const int fr = lane & 15, fq = lane >> 4;
  const int fco = (fq ^ ((lane >> 1) & 3)) * 8;
  const int brow_l = lane >> 2;
  const int bchunk = ((lane & 3) ^ ((lane >> 3) & 3)) * 8;

  const int wr = (w >> 2) * 64, wc = (w & 3) * 64;
  f4v acc[4][4];
#pragma unroll
  for (int i = 0; i < 4; ++i)
#pragma unroll
    for (int j = 0; j < 4; ++j) acc[i][j] = {0.f, 0.f, 0.f, 0.f};

  for (int k0 = 0; k0 < 64; k0 += 32) {
    __syncthreads();
#pragma unroll
    for (int i = 0; i < 2; ++i) {
      const int g = w * 2 + i;
      const int r = g * 16 + brow_l;
      gld_lds16(k + koff + (long long)r * ldk + k0 + bchunk,
                smB + g * 512 + lane * 8);
    }
    {
      const int r = w * 16 + brow_l;
      gld_lds16(q + qoff + (long long)r * ldq + k0 + bchunk,
                smA + w * 512 + lane * 8);
    }
    __syncthreads();
#pragma unroll
    for (int mi = 0; mi < 4; ++mi) {
      const bf8v a0 = *(const bf8v*)&smA[(wr + mi * 16 + fr) * 32 + fco];
#pragma unroll
      for (int nj = 0; nj < 4; ++nj) {
        const bf8v b0 = *(const bf8v*)&smB[(wc + nj * 16 + fr) * 32 + fco];
        acc[mi][nj] = __builtin_amdgcn_mfma_f32_16x16x32_bf16(a0, b0, acc[mi][nj], 0, 0, 0);
      }
    }
  }
  __syncthreads();

  if (w < 4) {
    const int r = w * 16 + brow_l;
    gld_lds16(vt + vbase + (long long)r * 256 + bchunk,
              smV + w * 512 + lane * 8);
  }

#pragma unroll
  for (int mi = 0; mi < 4; ++mi)
#pragma unroll
    for (int j = 0; j < 4; ++j) {
      float m = fmaxf(fmaxf(acc[mi][0][j], acc[mi][1][j]),
                      fmaxf(acc[mi][2][j], acc[mi][3][j]));
#pragma unroll
      for (int o2 = 1; o2 < 16; o2 <<= 1) m = fmaxf(m, __shfl_xor(m, o2));
      if (fr == 0) partial[(w & 3) * 128 + wr + mi * 16 + fq * 4 + j] = m;
    }
  __syncthreads();
  if (t < 128)
    rowmax[t] = fmaxf(fmaxf(partial[t], partial[128 + t]),
                      fmaxf(partial[256 + t], partial[384 + t]));
  __syncthreads();
#pragma unroll
  for (int mi = 0; mi < 4; ++mi)
#pragma unroll
    for (int j = 0; j < 4; ++j) {
      const int row = wr + mi * 16 + fq * 4 + j;
      const float rm = rowmax[row];
      float s = 0.f;
#pragma unroll
      for (int nj = 0; nj < 4; ++nj) {
        const float e = exp2f(acc[mi][nj][j] - rm);
        s += e;
        const int col = wc + nj * 16 + fr;
        const int kc = col >> 5, kloc = col & 31;
        Pbuf[kc * 4096 + row * 32 + (((kloc >> 3) ^ ((row >> 1) & 3)) * 8) +
             (kloc & 7)] = bf16_rne(e);
      }
#pragma unroll
      for (int o2 = 1; o2 < 16; o2 <<= 1) s += __shfl_xor(s, o2);
      if (fr == 0) partial[(w & 3) * 128 + row] = s;
    }
  __syncthreads();
  if (t < 128)
    rowsum[t] = 1.f / ((partial[t] + partial[128 + t]) +
                       (partial[256 + t] + partial[384 + t]));
  __syncthreads();

  const int wrp = (w >> 1) * 32, wcp = (w & 1) * 32;
  f4v acc2[2][2];
#pragma unroll
  for (int i = 0; i < 2; ++i)
#pragma unroll
    for (int j = 0; j < 2; ++j) acc2[i][j] = {0.f, 0.f, 0.f, 0.f};

  for (int kc = 0; kc < 8; ++kc) {
    const int cur = (kc & 1) * 2048;
    if (kc < 7 && w < 4) {
      const int r = w * 16 + brow_l;
      gld_lds16(vt + vbase + (long long)r * 256 + (kc + 1) * 32 + bchunk,
                smV + (2048 - cur) + w * 512 + lane * 8);
    }
#pragma unroll
    for (int mi = 0; mi < 2; ++mi) {
      const bf8v pa =
          *(const bf8v*)&Pbuf[kc * 4096 + (wrp + mi * 16 + fr) * 32 + fco];
#pragma unroll
      for (int nj = 0; nj < 2; ++nj) {
        const bf8v v0 =
            *(const bf8v*)&smV[cur + (wcp + nj * 16 + fr) * 32 + fco];
        acc2[mi][nj] = __builtin_amdgcn_mfma_f32_16x16x32_bf16(pa, v0, acc2[mi][nj], 0, 0, 0);
      }
    }
    __syncthreads();
  }
#pragma unroll
  for (int mi = 0; mi < 2; ++mi)
#pragma unroll
    for (int nj = 0; nj < 2; ++nj)
#pragma unroll
      for (int j = 0; j < 4; ++j) {
        const int row = wrp + mi * 16 + fq * 4 + j;
        const int col = wcp + nj * 16 + fr;
        o[ooff + (long long)row * 768 + col] =
            bf16_rne(acc2[mi][nj][j] * rowsum[row]);
      }
}

// ---------------- dual conv pool (bf16 in): k -> [b,h,t,dh], v -> [b,h,dh,t]
__global__ __launch_bounds__(256) void conv_dual_kernel(
    const u16* __restrict__ in, const float* __restrict__ w,
    u16* __restrict__ ok, u16* __restrict__ ovT, int total, int ld) {
  int idx = blockIdx.x * 256 + threadIdx.x;
  if (idx >= total) return;
  const int dh = idx & 63;
  int r = idx >> 6;
  const int tt = r & 1023; r >>= 10;
  const int h = r % 12;
  const int b = r / 12;
  const long long s = ((long long)(b * 4096 + 4 * tt)) * ld + h * 64 + dh;
  const float* wh = w + h * 4;
  float vk = 0.f, vv = 0.f;
#pragma unroll
  for (int j = 0; j < 4; ++j) {
    vk = fmaf(wh[j], bf16_to_f(in[s + j * ld]), vk);
    vv = fmaf(wh[j], bf16_to_f(in[s + 768 + j * ld]), vv);
  }
  ok[idx] = bf16_rne(vk);
  ovT[(((long long)(b * 12 + h)) * 64 + dh) * 1024 + tt] = bf16_rne(vv);
}

// ---------------- transpose: bf16 [4,256,ld] col-slice -> [b,h,dh,key] ------
__global__ __launch_bounds__(256) void transT_b2b_kernel(
    const u16* __restrict__ in, u16* __restrict__ o, int total, int ld) {
  int idx = blockIdx.x * 256 + threadIdx.x;
  if (idx >= total) return;
  const int key = idx & 255;
  int r = idx >> 8;
  const int dh = r & 63; r >>= 6;
  const int h = r % 12;
  const int b = r / 12;
  o[idx] = in[((long long)(b * 256 + key)) * ld + h * 64 + dh];
}

// ---------------- LayerNorm(a + b*maskf), b fp32 OR bf16 --------------------
template <int BBF16>
__global__ __launch_bounds__(256) void ln_kernel(
    const float* __restrict__ a, const float* __restrict__ bf,
    const u16* __restrict__ bb, const int* __restrict__ mask,
    float* __restrict__ out, u16* __restrict__ outb) {
  const long long row = blockIdx.x;
  const float* pa = a + row * 768;
  const float ms = mask ? (float)mask[row] : 1.f;
  __shared__ float buf[768];
  __shared__ float red[4];
  const int t = threadIdx.x;
  float lsum = 0.f;
#pragma unroll
  for (int i = t; i < 768; i += 256) {
    const float bvv = BBF16 ? bf16_to_f(bb[row * 768 + i]) : bf[row * 768 + i];
    const float v = fmaf(bvv, ms, pa[i]);
    buf[i] = v;
    lsum += v;
  }
  for (int o = 32; o; o >>= 1) lsum += __shfl_xor(lsum, o);
  if ((t & 63) == 0) red[t >> 6] = lsum;
  __syncthreads();
  const float mu = (red[0] + red[1] + red[2] + red[3]) * (1.f / 768.f);
  float lvar = 0.f;
#pragma unroll
  for (int i = t; i < 768; i += 256) {
    const float d = buf[i] - mu;
    lvar = fmaf(d, d, lvar);
  }
  __syncthreads();
  for (int o = 32; o; o >>= 1) lvar += __shfl_xor(lvar, o);
  if ((t & 63) == 0) red[t >> 6] = lvar;
  __syncthreads();
  const float var = (red[0] + red[1] + red[2] + red[3]) * (1.f / 768.f);
  const float rstd = rsqrtf(var + 1e-6f);
  float* po = out + row * 768;
  u16* pob = outb ? outb + row * 768 : nullptr;
#pragma unroll
  for (int i = t; i < 768; i += 256) {
    const float v = (buf[i] - mu) * rstd;
    po[i] = v;
    if (outb) pob[i] = bf16_rne(v);
  }
}

// ---------------- host ----------------
extern "C" void kernel_launch(void* const* d_in, const int* in_sizes, int n_in,
                              void* d_out, int out_size, void* d_ws,
                              size_t ws_size, hipStream_t stream) {
  const float* x = (const float*)d_in[0];
  const float* memory = (const float*)d_in[1];
  const int* mask = (const int*)d_in[2];
  const float* Wq = (const float*)d_in[3];
  const float* Wk = (const float*)d_in[4];
  const float* Wv = (const float*)d_in[5];
  const float* Wo = (const float*)d_in[6];
  const float* conv_w = (const float*)d_in[7];
  const float* Uq = (const float*)d_in[8];
  const float* Uk = (const float*)d_in[9];
  const float* Uv = (const float*)d_in[10];
  const float* Uo = (const float*)d_in[11];
  const float* W1 = (const float*)d_in[12];
  const float* W2 = (const float*)d_in[13];
  float* out = (float*)d_out;
  float* ws = (float*)d_ws;

  const int XR = 16384, MR = 1024, D = 768, MLP = 3072;
  const long long CB = 3145728;
  const int WD = 589824;
  const int WM = 2359296;

  float* A0 = ws + 0;         // 18.87M
  float* A1 = ws + 18874368;  // 12.58M
  float* A2 = ws + 31457280;  //  9.44M

  u16* xb    = (u16*)(A0 + 12582912);
  u16* kvqb  = (u16*)A0;
  u16* uattvb = (u16*)A1;
  u16* unpb  = (u16*)A0;
  float* qout1 = A0 + 6291456;
  u16* qout1b = (u16*)(out + 6291456);
  u16* hb    = (u16*)A1;
  float* ybuf = A2;

  u16* kpb  = (u16*)A2;
  u16* vpTb = kpb + 3145728;
  u16* qpb  = (u16*)(A2 + 3145728);
  u16* memb = qpb + 786432;
  u16* avmb = (u16*)(A2 + 3932160);
  u16* pkb  = avmb + 786432;
  float* packed = A2 + 4718592;
  u16* ukvb = (u16*)(A2 + 5505024);
  u16* uvTb = (u16*)(A2 + 6291456);
  u16* wp16 = (u16*)(A2 + 7077888);

  u16* Wkvqb = wp16;                      // [2304][768]
  u16* Wqb = wp16 + 2304 * 768;
  u16* Wob = Wqb + WD;
  u16* Ukvb2 = wp16;                      // [1536][768]
  u16* Uob = wp16 + 1536 * 768;
  u16* W1b = wp16;
  u16* W2b = wp16 + WM;

  const float UQS = 0.18033688011112042592f;  // 1/8 * log2(e)
  const float L2E = 1.4426950408889634074f;   // log2(e)

  // ---- pack phase: batched conversions ----
  {
    Cvt8 c{};
    const float* ss[7] = {x, memory, Wk, Wv, Uq, Wq, Wo};
    u16* dd[7] = {xb, memb, Wkvqb, Wkvqb + WD, Wkvqb + 2 * WD, Wqb, Wob};
    int nn[7] = {3145728, 196608, WD / 4, WD / 4, WD / 4, WD / 4, WD / 4};
    float sc[7] = {1.f, 1.f, 1.f, 1.f, UQS, 1.f, 1.f};
    int cum = 0;
    for (int i = 0; i < 7; ++i) {
      c.src[i] = ss[i]; c.dst[i] = dd[i]; c.n4[i] = nn[i]; c.sc[i] = sc[i];
      c.cum[i] = cum; cum += (nn[i] + 255) / 256;
    }
    c.cum[7] = cum; c.ns = 7;
    tobf16_multi_kernel<<<cum, 256, 0, stream>>>(c);
  }
  // merged kvq projection
  bgemm_kernel<0, 1><<<dim3(18, 128, 1), 256, 0, stream>>>(
      xb, Wkvqb, nullptr, kvqb, XR, 2304, D, D, D, 2304,
      0, 0, 0, 0, 0, 0, 1, 1.f);
  bgemm_kernel<0, 1><<<dim3(6, 8, 1), 256, 0, stream>>>(
      memb, Wqb, nullptr, qpb, MR, D, D, D, D, D, 0, 0, 0, 0, 0, 0, 1, L2E);
  conv_dual_kernel<<<12288, 256, 0, stream>>>(kvqb, conv_w, kpb, vpTb,
                                              3145728, 2304);
  {
    dim3 g(2, 1, 48);
    fused_pack_attn<<<g, 512, 0, stream>>>(qpb, kpb, vpTb, avmb);
  }
  bgemm_kernel<0, 2><<<dim3(6, 8, 1), 256, 0, stream>>>(
      avmb, Wob, packed, pkb, MR, D, D, D, D, D, 0, 0, 0, 0, 0, 0, 1, 1.f);
  ln_kernel<0><<<MR, 256, 0, stream>>>(memory, packed, nullptr, nullptr,
                                       out + 12582912, nullptr);

  // ---- unpack phase ----
  {
    Cvt8 c{};
    const float* ss[3] = {Uk, Uv, Uo};
    u16* dd[3] = {Ukvb2, Ukvb2 + WD, Uob};
    int cum = 0;
    for (int i = 0; i < 3; ++i) {
      c.src[i] = ss[i]; c.dst[i] = dd[i]; c.n4[i] = WD / 4; c.sc[i] = 1.f;
      c.cum[i] = cum; cum += (WD / 4 + 255) / 256;
    }
    c.cum[3] = cum; c.ns = 3;
    tobf16_multi_kernel<<<cum, 256, 0, stream>>>(c);
  }
  bgemm_kernel<0, 1><<<dim3(12, 8, 1), 256, 0, stream>>>(
      pkb, Ukvb2, nullptr, ukvb, MR, 1536, D, D, D, 1536,
      0, 0, 0, 0, 0, 0, 1, 1.f);
  transT_b2b_kernel<<<3072, 256, 0, stream>>>(ukvb + 768, uvTb, 786432, 1536);
  {
    dim3 g(32, 1, 48);
    fused_unpack_attn<<<g, 512, 0, stream>>>(kvqb + 1536, 2304, ukvb, 1536,
                                             uvTb, uattvb);
  }
  // Uo (z=4) -> unpb bf16; LN -> qout1 fp32 + bf16
  bgemm_kernel<0, 1><<<dim3(6, 32, 4), 256, 0, stream>>>(
      uattvb, Uob, nullptr, unpb, 4096, D, D, D, D, D,
      CB, 0, 0, 0, CB, 0, 1, 1.f);
  ln_kernel<1><<<XR, 256, 0, stream>>>(x, nullptr, unpb, mask, qout1, qout1b);

  // ---- FFN phase ----
  {
    Cvt8 c{};
    const float* ss[2] = {W1, W2};
    u16* dd[2] = {W1b, W2b};
    int cum = 0;
    for (int i = 0; i < 2; ++i) {
      c.src[i] = ss[i]; c.dst[i] = dd[i]; c.n4[i] = WM / 4; c.sc[i] = 1.f;
      c.cum[i] = cum; cum += (WM / 4 + 255) / 256;
    }
    c.cum[2] = cum; c.ns = 2;
    tobf16_multi_kernel<<<cum, 256, 0, stream>>>(c);
  }
  for (int c = 0; c < 2; ++c) {
    // W1+GELU
    bgemm_kernel<1, 1><<<dim3(24, 32, 2), 256, 0, stream>>>(
        qout1b + (long long)c * 2 * CB, W1b, nullptr, hb, 4096, MLP, D,
        D, D, MLP, CB, 0, 0, 0, 12582912, 0, 1, 1.f);
    // W2
    bgemm_kernel<0, 0><<<dim3(6, 32, 2), 256, 0, stream>>>(
        hb, W2b, ybuf, nullptr, 4096, D, MLP, MLP, MLP, D,
        12582912, 0, 0, 0, CB, 0, 1, 1.f);
    ln_kernel<0><<<8192, 256, 0, stream>>>(qout1 + (long long)c * 2 * CB, ybuf,
                                           nullptr, mask + c * 8192,
                                           out + (long long)c * 2 * CB, nullptr);
  }
}

// Round 17
// 664.188 us; speedup vs baseline: 1.0394x; 1.0394x over previous
//
#include <hip/hip_runtime.h>
#include <hip/hip_bf16.h>
#include <math.h>

// ----------------------------------------------------------------------------
// vMFLunaBlock v17: exact v15 (best: 643us) + s_setprio around attention MFMA
// clusters (T5). 3-buffer counted-vmcnt bgemm, BM=256 tall GEMMs / BM=128 rest.
// Workspace: 40,894,464 floats = 163.6 MB.
// ----------------------------------------------------------------------------

typedef unsigned short u16;
typedef __attribute__((ext_vector_type(8))) short bf8v;
typedef __attribute__((ext_vector_type(4))) float f4v;
typedef __attribute__((ext_vector_type(4))) unsigned short us4v;

#define AS1 __attribute__((address_space(1)))
#define AS3 __attribute__((address_space(3)))

__device__ __forceinline__ void gld_lds16(const void* g, void* l) {
  __builtin_amdgcn_global_load_lds((const AS1 unsigned int*)g,
                                   (AS3 unsigned int*)l, 16, 0, 0);
}

__device__ __forceinline__ u16 bf16_rne(float x) {
  unsigned u = __float_as_uint(x);
  return (u16)((u + 0x7fffu + ((u >> 16) & 1u)) >> 16);
}
__device__ __forceinline__ float bf16_to_f(u16 h) {
  return __uint_as_float(((unsigned)h) << 16);
}

// ---------------- batched fp32 -> bf16 convert (up to 8 segments) -----------
struct Cvt8 {
  const float* src[8];
  u16* dst[8];
  int n4[8];
  float sc[8];
  int cum[9];
  int ns;
};
__global__ __launch_bounds__(256) void tobf16_multi_kernel(Cvt8 c) {
  int b = blockIdx.x;
  int seg = 0;
  while (seg + 1 < c.ns && b >= c.cum[seg + 1]) ++seg;
  int i = (b - c.cum[seg]) * 256 + threadIdx.x;
  if (i >= c.n4[seg]) return;
  const float sc = c.sc[seg];
  float4 v = ((const float4*)c.src[seg])[i];
  us4v h;
  h[0] = bf16_rne(v.x * sc); h[1] = bf16_rne(v.y * sc);
  h[2] = bf16_rne(v.z * sc); h[3] = bf16_rne(v.w * sc);
  ((us4v*)c.dst[seg])[i] = h;
}

// ---------------- bf16 MFMA GEMM, triple-buffered counted-vmcnt -------------
// C = scale*(A @ B^T) [+GELU]. OMODE: 0=fp32, 1=bf16, 2=both.
// Tiles BM x BN (BM in {128,256}; BN=128); BM*2 threads, BM/32 waves
// arranged (BM/64) x 2; wave tile 64 x 64. Validated per-wave geometry.
template <int BM, int BN, int GELU, int OMODE>
__global__ __launch_bounds__(BM * 2) void bgemm_kernel(
    const u16* __restrict__ A, const u16* __restrict__ B,
    float* __restrict__ Cf, u16* __restrict__ Cb, int M, int N, int K,
    int lda, int ldb, int ldc, long long aSB, long long aSH, long long bSB,
    long long bSH, long long cSB, long long cSH, int HB, float scale) {
  constexpr int NJ = BN / 32;
  constexpr int NW = BM / 32;
  constexpr int LPB = (BN / 16) / NW;
  constexpr int VW = 2 + LPB;
  __shared__ u16 smA[3][BM * 32];
  __shared__ u16 smB[3][BN * 32];
  const int t = threadIdx.x;
  const int w = t >> 6, lane = t & 63;
  const int z = blockIdx.z;
  const int bb = z / HB, hh = z % HB;
  const u16* Ab = A + bb * aSB + hh * aSH;
  const u16* Bb = B + bb * bSB + hh * bSH;
  float* Cfb = (OMODE != 1) ? (Cf + bb * cSB + hh * cSH) : nullptr;
  u16* Cbb = (OMODE >= 1) ? (Cb + bb * cSB + hh * cSH) : nullptr;

  const int gx = gridDim.x;
  const int nwg = gx * gridDim.y;
  int f = blockIdx.x + gx * blockIdx.y;
  if ((nwg & 7) == 0) {
    const int cpx = nwg >> 3;
    f = (f & 7) * cpx + (f >> 3);
  }
  const int row0 = (f / gx) * BM, col0 = (f % gx) * BN;

  const int brow_l = lane >> 2;
  const int bchunk = ((lane & 3) ^ ((lane >> 3) & 3)) * 8;
  const int fr = lane & 15;
  const int fq = lane >> 4;
  const int fco = (fq ^ ((lane >> 1) & 3)) * 8;
  const int wr = (w >> 1) * 64, wc = (w & 1) * (BN / 2);

  f4v acc[4][NJ];
#pragma unroll
  for (int i = 0; i < 4; ++i)
#pragma unroll
    for (int j = 0; j < NJ; ++j) acc[i][j] = {0.f, 0.f, 0.f, 0.f};

  const int NT = K >> 5;

  auto stage = [&](int tile, int buf) {
    const int k0 = tile << 5;
#pragma unroll
    for (int i = 0; i < 2; ++i) {
      const int g = w * 2 + i;
      const int r = g * 16 + brow_l;
      gld_lds16(Ab + (long long)(row0 + r) * lda + k0 + bchunk,
                &smA[buf][g * 512 + lane * 8]);
    }
#pragma unroll
    for (int i = 0; i < LPB; ++i) {
      const int g = w * LPB + i;
      const int r = g * 16 + brow_l;
      gld_lds16(Bb + (long long)(col0 + r) * ldb + k0 + bchunk,
                &smB[buf][g * 512 + lane * 8]);
    }
  };
#define WAIT_L()                                            \
  do {                                                      \
    if constexpr (VW == 4)                                  \
      asm volatile("s_waitcnt vmcnt(4)" ::: "memory");      \
    else                                                    \
      asm volatile("s_waitcnt vmcnt(3)" ::: "memory");      \
  } while (0)

  stage(0, 0);
  if (NT > 1) {
    stage(1, 1);
    WAIT_L();
  } else {
    asm volatile("s_waitcnt vmcnt(0)" ::: "memory");
  }
  __builtin_amdgcn_sched_barrier(0);
  __builtin_amdgcn_s_barrier();

  int cur = 0;
  for (int tt = 0; tt < NT; ++tt) {
    const int nn2 = (cur + 2 >= 3) ? cur - 1 : cur + 2;
    if (tt + 2 < NT) stage(tt + 2, nn2);
    {
      bf8v af[4], bfr[NJ];
#pragma unroll
      for (int mi = 0; mi < 4; ++mi)
        af[mi] = *(const bf8v*)&smA[cur][(wr + mi * 16 + fr) * 32 + fco];
#pragma unroll
      for (int nj = 0; nj < NJ; ++nj)
        bfr[nj] = *(const bf8v*)&smB[cur][(wc + nj * 16 + fr) * 32 + fco];
      __builtin_amdgcn_s_setprio(1);
#pragma unroll
      for (int mi = 0; mi < 4; ++mi)
#pragma unroll
        for (int nj = 0; nj < NJ; ++nj)
          acc[mi][nj] = __builtin_amdgcn_mfma_f32_16x16x32_bf16(
              af[mi], bfr[nj], acc[mi][nj], 0, 0, 0);
      __builtin_amdgcn_s_setprio(0);
    }
    if (tt + 2 < NT) {
      WAIT_L();
    } else if (tt + 1 < NT) {
      asm volatile("s_waitcnt vmcnt(0)" ::: "memory");
    }
    __builtin_amdgcn_sched_barrier(0);
    __builtin_amdgcn_s_barrier();
    cur = (cur + 1 >= 3) ? 0 : cur + 1;
  }
#undef WAIT_L

#pragma unroll
  for (int mi = 0; mi < 4; ++mi)
#pragma unroll
    for (int nj = 0; nj < NJ; ++nj) {
      const int col = col0 + wc + nj * 16 + fr;
      const long long base =
          (long long)(row0 + wr + mi * 16 + fq * 4) * ldc + col;
#pragma unroll
      for (int j = 0; j < 4; ++j) {
        float v = acc[mi][nj][j] * scale;
        if (GELU) v = 0.5f * v * (1.f + erff(v * 0.70710678118654752f));
        const long long idx = base + (long long)j * ldc;
        if (OMODE != 1) Cfb[idx] = v;
        if (OMODE >= 1) Cbb[idx] = bf16_rne(v);
      }
    }
}

// ---------------- fused PACK attention (online softmax, exp2 domain) -------
__global__ __launch_bounds__(512) void fused_pack_attn(
    const u16* __restrict__ q, const u16* __restrict__ k,
    const u16* __restrict__ vt, u16* __restrict__ o) {
  __shared__ char pool[110080];
  u16* smQ = (u16*)pool;
  u16* smK = (u16*)(pool + 16384);
  u16* Pbuf = (u16*)(pool + 32768);
  u16* smV = (u16*)(pool + 98304);
  float* partial = (float*)(pool + 106496);
  float* mold = (float*)(pool + 108544);
  float* fbuf = (float*)(pool + 109056);
  float* srow = (float*)(pool + 109568);

  const int t = threadIdx.x;
  const int w = t >> 6, lane = t & 63;
  const int z = blockIdx.z;
  const int b = z / 12, h = z % 12;
  const int qrow0 = b * 256 + blockIdx.x * 128;
  const long long kvbase = ((long long)(b * 12 + h)) * 65536;

  const int fr = lane & 15, fq = lane >> 4;
  const int fco = (fq ^ ((lane >> 1) & 3)) * 8;
  const int brow_l = lane >> 2;
  const int bchunk = ((lane & 3) ^ ((lane >> 3) & 3)) * 8;
  const int wr = (w >> 2) * 64, wc = (w & 3) * 64;
  const int wrp = (w >> 1) * 32, wcp = (w & 1) * 32;

#pragma unroll
  for (int i = 0; i < 2; ++i) {
    const int g = w * 2 + i;
    const int plane = g >> 3, grp = g & 7;
    gld_lds16(q + (long long)(qrow0 + grp * 16 + brow_l) * 768 + h * 64 +
                  plane * 32 + bchunk,
              smQ + plane * 4096 + grp * 512 + lane * 8);
  }
  if (t < 128) {
    mold[t] = -3.0e38f;
    srow[t] = 0.f;
  }

  f4v acc2[2][2];
#pragma unroll
  for (int i = 0; i < 2; ++i)
#pragma unroll
    for (int j = 0; j < 2; ++j) acc2[i][j] = {0.f, 0.f, 0.f, 0.f};

  for (int kc = 0; kc < 4; ++kc) {
    f4v acc[4][4];
#pragma unroll
    for (int i = 0; i < 4; ++i)
#pragma unroll
      for (int j = 0; j < 4; ++j) acc[i][j] = {0.f, 0.f, 0.f, 0.f};

#pragma unroll
    for (int khalf = 0; khalf < 2; ++khalf) {
      __syncthreads();
#pragma unroll
      for (int i = 0; i < 2; ++i) {
        const int g = w * 2 + i;
        gld_lds16(k + kvbase +
                      (long long)(kc * 256 + g * 16 + brow_l) * 64 +
                      khalf * 32 + bchunk,
                  smK + g * 512 + lane * 8);
      }
      __syncthreads();
      __builtin_amdgcn_s_setprio(1);
#pragma unroll
      for (int mi = 0; mi < 4; ++mi) {
        const bf8v a0 =
            *(const bf8v*)&smQ[khalf * 4096 + (wr + mi * 16 + fr) * 32 + fco];
#pragma unroll
        for (int nj = 0; nj < 4; ++nj) {
          const bf8v b0 = *(const bf8v*)&smK[(wc + nj * 16 + fr) * 32 + fco];
          acc[mi][nj] =
              __builtin_amdgcn_mfma_f32_16x16x32_bf16(a0, b0, acc[mi][nj], 0, 0, 0);
        }
      }
      __builtin_amdgcn_s_setprio(0);
    }
    __syncthreads();

#pragma unroll
    for (int mi = 0; mi < 4; ++mi)
#pragma unroll
      for (int j = 0; j < 4; ++j) {
        float m = fmaxf(fmaxf(acc[mi][0][j], acc[mi][1][j]),
                        fmaxf(acc[mi][2][j], acc[mi][3][j]));
#pragma unroll
        for (int o2 = 1; o2 < 16; o2 <<= 1) m = fmaxf(m, __shfl_xor(m, o2));
        if (fr == 0) partial[(w & 3) * 128 + wr + mi * 16 + fq * 4 + j] = m;
      }
    __syncthreads();
    if (t < 128) {
      const float cm = fmaxf(fmaxf(partial[t], partial[128 + t]),
                             fmaxf(partial[256 + t], partial[384 + t]));
      const float mnew = fmaxf(mold[t], cm);
      fbuf[t] = exp2f(mold[t] - mnew);
      mold[t] = mnew;
    }
    __syncthreads();

#pragma unroll
    for (int mi = 0; mi < 4; ++mi)
#pragma unroll
      for (int j = 0; j < 4; ++j) {
        const int row = wr + mi * 16 + fq * 4 + j;
        const float rm = mold[row];
        float s = 0.f;
#pragma unroll
        for (int nj = 0; nj < 4; ++nj) {
          const float e = exp2f(acc[mi][nj][j] - rm);
          s += e;
          const int col = wc + nj * 16 + fr;
          const int kc2 = col >> 5, kloc = col & 31;
          Pbuf[kc2 * 4096 + row * 32 + (((kloc >> 3) ^ ((row >> 1) & 3)) * 8) +
               (kloc & 7)] = bf16_rne(e);
        }
#pragma unroll
        for (int o2 = 1; o2 < 16; o2 <<= 1) s += __shfl_xor(s, o2);
        if (fr == 0) partial[(w & 3) * 128 + row] = s;
      }
    if (w < 4) {
      gld_lds16(vt + kvbase + (long long)(w * 16 + brow_l) * 1024 + kc * 256 +
                    bchunk,
                smV + w * 512 + lane * 8);
    }
    __syncthreads();
    if (t < 128)
      srow[t] = srow[t] * fbuf[t] +
                ((partial[t] + partial[128 + t]) +
                 (partial[256 + t] + partial[384 + t]));
    __syncthreads();

#pragma unroll
    for (int mi = 0; mi < 2; ++mi)
#pragma unroll
      for (int j = 0; j < 4; ++j) {
        const float fr_ = fbuf[wrp + mi * 16 + fq * 4 + j];
        acc2[mi][0][j] *= fr_;
        acc2[mi][1][j] *= fr_;
      }

    for (int sk = 0; sk < 8; ++sk) {
      const int cur = (sk & 1) * 2048;
      if (sk < 7 && w < 4) {
        gld_lds16(vt + kvbase + (long long)(w * 16 + brow_l) * 1024 +
                      kc * 256 + (sk + 1) * 32 + bchunk,
                  smV + (2048 - cur) + w * 512 + lane * 8);
      }
      __builtin_amdgcn_s_setprio(1);
#pragma unroll
      for (int mi = 0; mi < 2; ++mi) {
        const bf8v pa =
            *(const bf8v*)&Pbuf[sk * 4096 + (wrp + mi * 16 + fr) * 32 + fco];
#pragma unroll
        for (int nj = 0; nj < 2; ++nj) {
          const bf8v v0 =
              *(const bf8v*)&smV[cur + (wcp + nj * 16 + fr) * 32 + fco];
          acc2[mi][nj] =
              __builtin_amdgcn_mfma_f32_16x16x32_bf16(pa, v0, acc2[mi][nj], 0, 0, 0);
        }
      }
      __builtin_amdgcn_s_setprio(0);
      __syncthreads();
    }
  }

  if (t < 128) fbuf[t] = 1.f / srow[t];
  __syncthreads();
  const long long ooff = (long long)qrow0 * 768 + h * 64;
#pragma unroll
  for (int mi = 0; mi < 2; ++mi)
#pragma unroll
    for (int nj = 0; nj < 2; ++nj)
#pragma unroll
      for (int j = 0; j < 4; ++j) {
        const int row = wrp + mi * 16 + fq * 4 + j;
        const int col = wcp + nj * 16 + fr;
        o[ooff + (long long)row * 768 + col] =
            bf16_rne(acc2[mi][nj][j] * fbuf[row]);
      }
}

// ---------------- fused unpack attention (bf16, strided q/k) ----------------
__global__ __launch_bounds__(512) void fused_unpack_attn(
    const u16* __restrict__ q, int ldq, const u16* __restrict__ k, int ldk,
    const u16* __restrict__ vt, u16* __restrict__ o) {
  __shared__ char pool[76800];
  u16* smA = (u16*)pool;
  u16* smB = (u16*)(pool + 8192);
  u16* Pbuf = (u16*)pool;
  u16* smV = (u16*)(pool + 65536);
  float* partial = (float*)(pool + 73728);
  float* rowmax = (float*)(pool + 75776);
  float* rowsum = (float*)(pool + 76288);

  const int t = threadIdx.x;
  const int w = t >> 6, lane = t & 63;
  const int z = blockIdx.z;
  const int b = z / 12, h = z % 12;
  const int q0 = blockIdx.x * 128;

  const long long qoff = (long long)(b * 4096 + q0) * ldq + h * 64;
  const long long koff = (long long)(b * 256) * ldk + h * 64;
  const long long vbase = ((long long)(b * 12 + h)) * 16384;
  const long long ooff = (long long)(b * 4096 + q0) * 768 + h * 64;

  const int fr = lane & 15, fq = lane >> 4;
  const int fco = (fq ^ ((lane >> 1) & 3)) * 8;
  const int brow_l = lane >> 2;
  const int bchunk = ((lane & 3) ^ ((lane >> 3) & 3)) * 8;

  const int wr = (w >> 2) * 64, wc = (w & 3) * 64;
  f4v acc[4][4];
#pragma unroll
  for (int i = 0; i < 4; ++i)
#pragma unroll
    for (int j = 0; j < 4; ++j) acc[i][j] = {0.f, 0.f, 0.f, 0.f};

  for (int k0 = 0; k0 < 64; k0 += 32) {
    __syncthreads();
#pragma unroll
    for (int i = 0; i < 2; ++i) {
      const int g = w * 2 + i;
      const int r = g * 16 + brow_l;
      gld_lds16(k + koff + (long long)r * ldk + k0 + bchunk,
                smB + g * 512 + lane * 8);
    }
    {
      const int r = w * 16 + brow_l;
      gld_lds16(q + qoff + (long long)r * ldq + k0 + bchunk,
                smA + w * 512 + lane * 8);
    }
    __syncthreads();
    __builtin_amdgcn_s_setprio(1);
#pragma unroll
    for (int mi = 0; mi < 4; ++mi) {
      const bf8v a0 = *(const bf8v*)&smA[(wr + mi * 16 + fr) * 32 + fco];
#pragma unroll
      for (int nj = 0; nj < 4; ++nj) {
        const bf8v b0 = *(const bf8v*)&smB[(wc + nj * 16 + fr) * 32 + fco];
        acc[mi][nj] = __builtin_amdgcn_mfma_f32_16x16x32_bf16(a0, b0, acc[mi][nj], 0, 0, 0);
      }
    }
    __builtin_amdgcn_s_setprio(0);
  }
  __syncthreads();

  if (w < 4) {
    const int r = w * 16 + brow_l;
    gld_lds16(vt + vbase + (long long)r * 256 + bchunk,
              smV + w * 512 + lane * 8);
  }

#pragma unroll
  for (int mi = 0; mi < 4; ++mi)
#pragma unroll
    for (int j = 0; j < 4; ++j) {
      float m = fmaxf(fmaxf(acc[mi][0][j], acc[mi][1][j]),
                      fmaxf(acc[mi][2][j], acc[mi][3][j]));
#pragma unroll
      for (int o2 = 1; o2 < 16; o2 <<= 1) m = fmaxf(m, __shfl_xor(m, o2));
      if (fr == 0) partial[(w & 3) * 128 + wr + mi * 16 + fq * 4 + j] = m;
    }
  __syncthreads();
  if (t < 128)
    rowmax[t] = fmaxf(fmaxf(partial[t], partial[128 + t]),
                      fmaxf(partial[256 + t], partial[384 + t]));
  __syncthreads();
#pragma unroll
  for (int mi = 0; mi < 4; ++mi)
#pragma unroll
    for (int j = 0; j < 4; ++j) {
      const int row = wr + mi * 16 + fq * 4 + j;
      const float rm = rowmax[row];
      float s = 0.f;
#pragma unroll
      for (int nj = 0; nj < 4; ++nj) {
        const float e = exp2f(acc[mi][nj][j] - rm);
        s += e;
        const int col = wc + nj * 16 + fr;
        const int kc = col >> 5, kloc = col & 31;
        Pbuf[kc * 4096 + row * 32 + (((kloc >> 3) ^ ((row >> 1) & 3)) * 8) +
             (kloc & 7)] = bf16_rne(e);
      }
#pragma unroll
      for (int o2 = 1; o2 < 16; o2 <<= 1) s += __shfl_xor(s, o2);
      if (fr == 0) partial[(w & 3) * 128 + row] = s;
    }
  __syncthreads();
  if (t < 128)
    rowsum[t] = 1.f / ((partial[t] + partial[128 + t]) +
                       (partial[256 + t] + partial[384 + t]));
  __syncthreads();

  const int wrp = (w >> 1) * 32, wcp = (w & 1) * 32;
  f4v acc2[2][2];
#pragma unroll
  for (int i = 0; i < 2; ++i)
#pragma unroll
    for (int j = 0; j < 2; ++j) acc2[i][j] = {0.f, 0.f, 0.f, 0.f};

  for (int kc = 0; kc < 8; ++kc) {
    const int cur = (kc & 1) * 2048;
    if (kc < 7 && w < 4) {
      const int r = w * 16 + brow_l;
      gld_lds16(vt + vbase + (long long)r * 256 + (kc + 1) * 32 + bchunk,
                smV + (2048 - cur) + w * 512 + lane * 8);
    }
    __builtin_amdgcn_s_setprio(1);
#pragma unroll
    for (int mi = 0; mi < 2; ++mi) {
      const bf8v pa =
          *(const bf8v*)&Pbuf[kc * 4096 + (wrp + mi * 16 + fr) * 32 + fco];
#pragma unroll
      for (int nj = 0; nj < 2; ++nj) {
        const bf8v v0 =
            *(const bf8v*)&smV[cur + (wcp + nj * 16 + fr) * 32 + fco];
        acc2[mi][nj] = __builtin_amdgcn_mfma_f32_16x16x32_bf16(pa, v0, acc2[mi][nj], 0, 0, 0);
      }
    }
    __builtin_amdgcn_s_setprio(0);
    __syncthreads();
  }
#pragma unroll
  for (int mi = 0; mi < 2; ++mi)
#pragma unroll
    for (int nj = 0; nj < 2; ++nj)
#pragma unroll
      for (int j = 0; j < 4; ++j) {
        const int row = wrp + mi * 16 + fq * 4 + j;
        const int col = wcp + nj * 16 + fr;
        o[ooff + (long long)row * 768 + col] =
            bf16_rne(acc2[mi][nj][j] * rowsum[row]);
      }
}

// ---------------- dual conv pool (bf16 in): k -> [b,h,t,dh], v -> [b,h,dh,t]
__global__ __launch_bounds__(256) void conv_dual_kernel(
    const u16* __restrict__ in, const float* __restrict__ w,
    u16* __restrict__ ok, u16* __restrict__ ovT, int total, int ld) {
  int idx = blockIdx.x * 256 + threadIdx.x;
  if (idx >= total) return;
  const int dh = idx & 63;
  int r = idx >> 6;
  const int tt = r & 1023; r >>= 10;
  const int h = r % 12;
  const int b = r / 12;
  const long long s = ((long long)(b * 4096 + 4 * tt)) * ld + h * 64 + dh;
  const float* wh = w + h * 4;
  float vk = 0.f, vv = 0.f;
#pragma unroll
  for (int j = 0; j < 4; ++j) {
    vk = fmaf(wh[j], bf16_to_f(in[s + j * ld]), vk);
    vv = fmaf(wh[j], bf16_to_f(in[s + 768 + j * ld]), vv);
  }
  ok[idx] = bf16_rne(vk);
  ovT[(((long long)(b * 12 + h)) * 64 + dh) * 1024 + tt] = bf16_rne(vv);
}

// ---------------- transpose: bf16 [4,256,ld] col-slice -> [b,h,dh,key] ------
__global__ __launch_bounds__(256) void transT_b2b_kernel(
    const u16* __restrict__ in, u16* __restrict__ o, int total, int ld) {
  int idx = blockIdx.x * 256 + threadIdx.x;
  if (idx >= total) return;
  const int key = idx & 255;
  int r = idx >> 8;
  const int dh = r & 63; r >>= 6;
  const int h = r % 12;
  const int b = r / 12;
  o[idx] = in[((long long)(b * 256 + key)) * ld + h * 64 + dh];
}

// ---------------- LayerNorm(a + b*maskf), b fp32 OR bf16 --------------------
template <int BBF16>
__global__ __launch_bounds__(256) void ln_kernel(
    const float* __restrict__ a, const float* __restrict__ bf,
    const u16* __restrict__ bb, const int* __restrict__ mask,
    float* __restrict__ out, u16* __restrict__ outb) {
  const long long row = blockIdx.x;
  const float* pa = a + row * 768;
  const float ms = mask ? (float)mask[row] : 1.f;
  __shared__ float buf[768];
  __shared__ float red[4];
  const int t = threadIdx.x;
  float lsum = 0.f;
#pragma unroll
  for (int i = t; i < 768; i += 256) {
    const float bvv = BBF16 ? bf16_to_f(bb[row * 768 + i]) : bf[row * 768 + i];
    const float v = fmaf(bvv, ms, pa[i]);
    buf[i] = v;
    lsum += v;
  }
  for (int o = 32; o; o >>= 1) lsum += __shfl_xor(lsum, o);
  if ((t & 63) == 0) red[t >> 6] = lsum;
  __syncthreads();
  const float mu = (red[0] + red[1] + red[2] + red[3]) * (1.f / 768.f);
  float lvar = 0.f;
#pragma unroll
  for (int i = t; i < 768; i += 256) {
    const float d = buf[i] - mu;
    lvar = fmaf(d, d, lvar);
  }
  __syncthreads();
  for (int o = 32; o; o >>= 1) lvar += __shfl_xor(lvar, o);
  if ((t & 63) == 0) red[t >> 6] = lvar;
  __syncthreads();
  const float var = (red[0] + red[1] + red[2] + red[3]) * (1.f / 768.f);
  const float rstd = rsqrtf(var + 1e-6f);
  float* po = out + row * 768;
  u16* pob = outb ? outb + row * 768 : nullptr;
#pragma unroll
  for (int i = t; i < 768; i += 256) {
    const float v = (buf[i] - mu) * rstd;
    po[i] = v;
    if (outb) pob[i] = bf16_rne(v);
  }
}

// ---------------- host ----------------
extern "C" void kernel_launch(void* const* d_in, const int* in_sizes, int n_in,
                              void* d_out, int out_size, void* d_ws,
                              size_t ws_size, hipStream_t stream) {
  const float* x = (const float*)d_in[0];
  const float* memory = (const float*)d_in[1];
  const int* mask = (const int*)d_in[2];
  const float* Wq = (const float*)d_in[3];
  const float* Wk = (const float*)d_in[4];
  const float* Wv = (const float*)d_in[5];
  const float* Wo = (const float*)d_in[6];
  const float* conv_w = (const float*)d_in[7];
  const float* Uq = (const float*)d_in[8];
  const float* Uk = (const float*)d_in[9];
  const float* Uv = (const float*)d_in[10];
  const float* Uo = (const float*)d_in[11];
  const float* W1 = (const float*)d_in[12];
  const float* W2 = (const float*)d_in[13];
  float* out = (float*)d_out;
  float* ws = (float*)d_ws;

  const int XR = 16384, MR = 1024, D = 768, MLP = 3072;
  const long long CB = 3145728;
  const int WD = 589824;
  const int WM = 2359296;

  float* A0 = ws + 0;         // 18.87M
  float* A1 = ws + 18874368;  // 12.58M
  float* A2 = ws + 31457280;  //  9.44M

  u16* xb    = (u16*)(A0 + 12582912);
  u16* kvqb  = (u16*)A0;
  u16* uattvb = (u16*)A1;
  u16* unpb  = (u16*)A0;
  float* qout1 = A0 + 6291456;
  u16* qout1b = (u16*)(out + 6291456);
  u16* hb    = (u16*)A1;
  float* ybuf = A2;

  u16* kpb  = (u16*)A2;
  u16* vpTb = kpb + 3145728;
  u16* qpb  = (u16*)(A2 + 3145728);
  u16* memb = qpb + 786432;
  u16* avmb = (u16*)(A2 + 3932160);
  u16* pkb  = avmb + 786432;
  float* packed = A2 + 4718592;
  u16* ukvb = (u16*)(A2 + 5505024);
  u16* uvTb = (u16*)(A2 + 6291456);
  u16* wp16 = (u16*)(A2 + 7077888);

  u16* Wkvqb = wp16;                      // [2304][768]
  u16* Wqb = wp16 + 2304 * 768;
  u16* Wob = Wqb + WD;
  u16* Ukvb2 = wp16;                      // [1536][768]
  u16* Uob = wp16 + 1536 * 768;
  u16* W1b = wp16;
  u16* W2b = wp16 + WM;

  const float UQS = 0.18033688011112042592f;  // 1/8 * log2(e)
  const float L2E = 1.4426950408889634074f;   // log2(e)

  // ---- pack phase: batched conversions ----
  {
    Cvt8 c{};
    const float* ss[7] = {x, memory, Wk, Wv, Uq, Wq, Wo};
    u16* dd[7] = {xb, memb, Wkvqb, Wkvqb + WD, Wkvqb + 2 * WD, Wqb, Wob};
    int nn[7] = {3145728, 196608, WD / 4, WD / 4, WD / 4, WD / 4, WD / 4};
    float sc[7] = {1.f, 1.f, 1.f, 1.f, UQS, 1.f, 1.f};
    int cum = 0;
    for (int i = 0; i < 7; ++i) {
      c.src[i] = ss[i]; c.dst[i] = dd[i]; c.n4[i] = nn[i]; c.sc[i] = sc[i];
      c.cum[i] = cum; cum += (nn[i] + 255) / 256;
    }
    c.cum[7] = cum; c.ns = 7;
    tobf16_multi_kernel<<<cum, 256, 0, stream>>>(c);
  }
  // merged kvq projection (BM=256, 512 thr, 8 waves)
  bgemm_kernel<256, 128, 0, 1><<<dim3(18, 64, 1), 512, 0, stream>>>(
      xb, Wkvqb, nullptr, kvqb, XR, 2304, D, D, D, 2304,
      0, 0, 0, 0, 0, 0, 1, 1.f);
  bgemm_kernel<128, 128, 0, 1><<<dim3(6, 8, 1), 256, 0, stream>>>(
      memb, Wqb, nullptr, qpb, MR, D, D, D, D, D, 0, 0, 0, 0, 0, 0, 1, L2E);
  conv_dual_kernel<<<12288, 256, 0, stream>>>(kvqb, conv_w, kpb, vpTb,
                                              3145728, 2304);
  {
    dim3 g(2, 1, 48);
    fused_pack_attn<<<g, 512, 0, stream>>>(qpb, kpb, vpTb, avmb);
  }
  bgemm_kernel<128, 128, 0, 2><<<dim3(6, 8, 1), 256, 0, stream>>>(
      avmb, Wob, packed, pkb, MR, D, D, D, D, D, 0, 0, 0, 0, 0, 0, 1, 1.f);
  ln_kernel<0><<<MR, 256, 0, stream>>>(memory, packed, nullptr, nullptr,
                                       out + 12582912, nullptr);

  // ---- unpack phase ----
  {
    Cvt8 c{};
    const float* ss[3] = {Uk, Uv, Uo};
    u16* dd[3] = {Ukvb2, Ukvb2 + WD, Uob};
    int cum = 0;
    for (int i = 0; i < 3; ++i) {
      c.src[i] = ss[i]; c.dst[i] = dd[i]; c.n4[i] = WD / 4; c.sc[i] = 1.f;
      c.cum[i] = cum; cum += (WD / 4 + 255) / 256;
    }
    c.cum[3] = cum; c.ns = 3;
    tobf16_multi_kernel<<<cum, 256, 0, stream>>>(c);
  }
  bgemm_kernel<128, 128, 0, 1><<<dim3(12, 8, 1), 256, 0, stream>>>(
      pkb, Ukvb2, nullptr, ukvb, MR, 1536, D, D, D, 1536,
      0, 0, 0, 0, 0, 0, 1, 1.f);
  transT_b2b_kernel<<<3072, 256, 0, stream>>>(ukvb + 768, uvTb, 786432, 1536);
  {
    dim3 g(32, 1, 48);
    fused_unpack_attn<<<g, 512, 0, stream>>>(kvqb + 1536, 2304, ukvb, 1536,
                                             uvTb, uattvb);
  }
  // Uo (BM=256, z=4) -> unpb bf16; LN -> qout1 fp32 + bf16
  bgemm_kernel<256, 128, 0, 1><<<dim3(6, 16, 4), 512, 0, stream>>>(
      uattvb, Uob, nullptr, unpb, 4096, D, D, D, D, D,
      CB, 0, 0, 0, CB, 0, 1, 1.f);
  ln_kernel<1><<<XR, 256, 0, stream>>>(x, nullptr, unpb, mask, qout1, qout1b);

  // ---- FFN phase ----
  {
    Cvt8 c{};
    const float* ss[2] = {W1, W2};
    u16* dd[2] = {W1b, W2b};
    int cum = 0;
    for (int i = 0; i < 2; ++i) {
      c.src[i] = ss[i]; c.dst[i] = dd[i]; c.n4[i] = WM / 4; c.sc[i] = 1.f;
      c.cum[i] = cum; cum += (WM / 4 + 255) / 256;
    }
    c.cum[2] = cum; c.ns = 2;
    tobf16_multi_kernel<<<cum, 256, 0, stream>>>(c);
  }
  for (int c = 0; c < 2; ++c) {
    // W1+GELU (BM=256)
    bgemm_kernel<256, 128, 1, 1><<<dim3(24, 16, 2), 512, 0, stream>>>(
        qout1b + (long long)c * 2 * CB, W1b, nullptr, hb, 4096, MLP, D,
        D, D, MLP, CB, 0, 0, 0, 12582912, 0, 1, 1.f);
    // W2 (BM=128)
    bgemm_kernel<128, 128, 0, 0><<<dim3(6, 32, 2), 256, 0, stream>>>(
        hb, W2b, ybuf, nullptr, 4096, D, MLP, MLP, MLP, D,
        12582912, 0, 0, 0, CB, 0, 1, 1.f);
    ln_kernel<0><<<8192, 256, 0, stream>>>(qout1 + (long long)c * 2 * CB, ybuf,
                                           nullptr, mask + c * 8192,
                                           out + (long long)c * 2 * CB, nullptr);
  }
}

// Round 18
// 634.742 us; speedup vs baseline: 1.0876x; 1.0464x over previous
//
#include <hip/hip_runtime.h>
#include <hip/hip_bf16.h>
#include <math.h>

// ----------------------------------------------------------------------------
// vMFLunaBlock v18 == v15 exactly (measured best: 643us). Attn setprio from
// v17 removed (measured -21us regression; barrier-locked waves lack the
// role diversity T5 needs). bgemm: 3-buffer counted-vmcnt, BM=256 tall /
// BM=128 rest, XCD swizzle, setprio on GEMM MFMA cluster.
// Workspace: 40,894,464 floats = 163.6 MB.
// ----------------------------------------------------------------------------

typedef unsigned short u16;
typedef __attribute__((ext_vector_type(8))) short bf8v;
typedef __attribute__((ext_vector_type(4))) float f4v;
typedef __attribute__((ext_vector_type(4))) unsigned short us4v;

#define AS1 __attribute__((address_space(1)))
#define AS3 __attribute__((address_space(3)))

__device__ __forceinline__ void gld_lds16(const void* g, void* l) {
  __builtin_amdgcn_global_load_lds((const AS1 unsigned int*)g,
                                   (AS3 unsigned int*)l, 16, 0, 0);
}

__device__ __forceinline__ u16 bf16_rne(float x) {
  unsigned u = __float_as_uint(x);
  return (u16)((u + 0x7fffu + ((u >> 16) & 1u)) >> 16);
}
__device__ __forceinline__ float bf16_to_f(u16 h) {
  return __uint_as_float(((unsigned)h) << 16);
}

// ---------------- batched fp32 -> bf16 convert (up to 8 segments) -----------
struct Cvt8 {
  const float* src[8];
  u16* dst[8];
  int n4[8];
  float sc[8];
  int cum[9];
  int ns;
};
__global__ __launch_bounds__(256) void tobf16_multi_kernel(Cvt8 c) {
  int b = blockIdx.x;
  int seg = 0;
  while (seg + 1 < c.ns && b >= c.cum[seg + 1]) ++seg;
  int i = (b - c.cum[seg]) * 256 + threadIdx.x;
  if (i >= c.n4[seg]) return;
  const float sc = c.sc[seg];
  float4 v = ((const float4*)c.src[seg])[i];
  us4v h;
  h[0] = bf16_rne(v.x * sc); h[1] = bf16_rne(v.y * sc);
  h[2] = bf16_rne(v.z * sc); h[3] = bf16_rne(v.w * sc);
  ((us4v*)c.dst[seg])[i] = h;
}

// ---------------- bf16 MFMA GEMM, triple-buffered counted-vmcnt -------------
// C = scale*(A @ B^T) [+GELU]. OMODE: 0=fp32, 1=bf16, 2=both.
// Tiles BM x BN (BM in {128,256}; BN=128); BM*2 threads, BM/32 waves
// arranged (BM/64) x 2; wave tile 64 x 64.
template <int BM, int BN, int GELU, int OMODE>
__global__ __launch_bounds__(BM * 2) void bgemm_kernel(
    const u16* __restrict__ A, const u16* __restrict__ B,
    float* __restrict__ Cf, u16* __restrict__ Cb, int M, int N, int K,
    int lda, int ldb, int ldc, long long aSB, long long aSH, long long bSB,
    long long bSH, long long cSB, long long cSH, int HB, float scale) {
  constexpr int NJ = BN / 32;
  constexpr int NW = BM / 32;
  constexpr int LPB = (BN / 16) / NW;
  constexpr int VW = 2 + LPB;
  __shared__ u16 smA[3][BM * 32];
  __shared__ u16 smB[3][BN * 32];
  const int t = threadIdx.x;
  const int w = t >> 6, lane = t & 63;
  const int z = blockIdx.z;
  const int bb = z / HB, hh = z % HB;
  const u16* Ab = A + bb * aSB + hh * aSH;
  const u16* Bb = B + bb * bSB + hh * bSH;
  float* Cfb = (OMODE != 1) ? (Cf + bb * cSB + hh * cSH) : nullptr;
  u16* Cbb = (OMODE >= 1) ? (Cb + bb * cSB + hh * cSH) : nullptr;

  const int gx = gridDim.x;
  const int nwg = gx * gridDim.y;
  int f = blockIdx.x + gx * blockIdx.y;
  if ((nwg & 7) == 0) {
    const int cpx = nwg >> 3;
    f = (f & 7) * cpx + (f >> 3);
  }
  const int row0 = (f / gx) * BM, col0 = (f % gx) * BN;

  const int brow_l = lane >> 2;
  const int bchunk = ((lane & 3) ^ ((lane >> 3) & 3)) * 8;
  const int fr = lane & 15;
  const int fq = lane >> 4;
  const int fco = (fq ^ ((lane >> 1) & 3)) * 8;
  const int wr = (w >> 1) * 64, wc = (w & 1) * (BN / 2);

  f4v acc[4][NJ];
#pragma unroll
  for (int i = 0; i < 4; ++i)
#pragma unroll
    for (int j = 0; j < NJ; ++j) acc[i][j] = {0.f, 0.f, 0.f, 0.f};

  const int NT = K >> 5;

  auto stage = [&](int tile, int buf) {
    const int k0 = tile << 5;
#pragma unroll
    for (int i = 0; i < 2; ++i) {
      const int g = w * 2 + i;
      const int r = g * 16 + brow_l;
      gld_lds16(Ab + (long long)(row0 + r) * lda + k0 + bchunk,
                &smA[buf][g * 512 + lane * 8]);
    }
#pragma unroll
    for (int i = 0; i < LPB; ++i) {
      const int g = w * LPB + i;
      const int r = g * 16 + brow_l;
      gld_lds16(Bb + (long long)(col0 + r) * ldb + k0 + bchunk,
                &smB[buf][g * 512 + lane * 8]);
    }
  };
#define WAIT_L()                                            \
  do {                                                      \
    if constexpr (VW == 4)                                  \
      asm volatile("s_waitcnt vmcnt(4)" ::: "memory");      \
    else                                                    \
      asm volatile("s_waitcnt vmcnt(3)" ::: "memory");      \
  } while (0)

  stage(0, 0);
  if (NT > 1) {
    stage(1, 1);
    WAIT_L();
  } else {
    asm volatile("s_waitcnt vmcnt(0)" ::: "memory");
  }
  __builtin_amdgcn_sched_barrier(0);
  __builtin_amdgcn_s_barrier();

  int cur = 0;
  for (int tt = 0; tt < NT; ++tt) {
    const int nn2 = (cur + 2 >= 3) ? cur - 1 : cur + 2;
    if (tt + 2 < NT) stage(tt + 2, nn2);
    {
      bf8v af[4], bfr[NJ];
#pragma unroll
      for (int mi = 0; mi < 4; ++mi)
        af[mi] = *(const bf8v*)&smA[cur][(wr + mi * 16 + fr) * 32 + fco];
#pragma unroll
      for (int nj = 0; nj < NJ; ++nj)
        bfr[nj] = *(const bf8v*)&smB[cur][(wc + nj * 16 + fr) * 32 + fco];
      __builtin_amdgcn_s_setprio(1);
#pragma unroll
      for (int mi = 0; mi < 4; ++mi)
#pragma unroll
        for (int nj = 0; nj < NJ; ++nj)
          acc[mi][nj] = __builtin_amdgcn_mfma_f32_16x16x32_bf16(
              af[mi], bfr[nj], acc[mi][nj], 0, 0, 0);
      __builtin_amdgcn_s_setprio(0);
    }
    if (tt + 2 < NT) {
      WAIT_L();
    } else if (tt + 1 < NT) {
      asm volatile("s_waitcnt vmcnt(0)" ::: "memory");
    }
    __builtin_amdgcn_sched_barrier(0);
    __builtin_amdgcn_s_barrier();
    cur = (cur + 1 >= 3) ? 0 : cur + 1;
  }
#undef WAIT_L

#pragma unroll
  for (int mi = 0; mi < 4; ++mi)
#pragma unroll
    for (int nj = 0; nj < NJ; ++nj) {
      const int col = col0 + wc + nj * 16 + fr;
      const long long base =
          (long long)(row0 + wr + mi * 16 + fq * 4) * ldc + col;
#pragma unroll
      for (int j = 0; j < 4; ++j) {
        float v = acc[mi][nj][j] * scale;
        if (GELU) v = 0.5f * v * (1.f + erff(v * 0.70710678118654752f));
        const long long idx = base + (long long)j * ldc;
        if (OMODE != 1) Cfb[idx] = v;
        if (OMODE >= 1) Cbb[idx] = bf16_rne(v);
      }
    }
}

// ---------------- fused PACK attention (online softmax, exp2 domain) -------
__global__ __launch_bounds__(512) void fused_pack_attn(
    const u16* __restrict__ q, const u16* __restrict__ k,
    const u16* __restrict__ vt, u16* __restrict__ o) {
  __shared__ char pool[110080];
  u16* smQ = (u16*)pool;
  u16* smK = (u16*)(pool + 16384);
  u16* Pbuf = (u16*)(pool + 32768);
  u16* smV = (u16*)(pool + 98304);
  float* partial = (float*)(pool + 106496);
  float* mold = (float*)(pool + 108544);
  float* fbuf = (float*)(pool + 109056);
  float* srow = (float*)(pool + 109568);

  const int t = threadIdx.x;
  const int w = t >> 6, lane = t & 63;
  const int z = blockIdx.z;
  const int b = z / 12, h = z % 12;
  const int qrow0 = b * 256 + blockIdx.x * 128;
  const long long kvbase = ((long long)(b * 12 + h)) * 65536;

  const int fr = lane & 15, fq = lane >> 4;
  const int fco = (fq ^ ((lane >> 1) & 3)) * 8;
  const int brow_l = lane >> 2;
  const int bchunk = ((lane & 3) ^ ((lane >> 3) & 3)) * 8;
  const int wr = (w >> 2) * 64, wc = (w & 3) * 64;
  const int wrp = (w >> 1) * 32, wcp = (w & 1) * 32;

#pragma unroll
  for (int i = 0; i < 2; ++i) {
    const int g = w * 2 + i;
    const int plane = g >> 3, grp = g & 7;
    gld_lds16(q + (long long)(qrow0 + grp * 16 + brow_l) * 768 + h * 64 +
                  plane * 32 + bchunk,
              smQ + plane * 4096 + grp * 512 + lane * 8);
  }
  if (t < 128) {
    mold[t] = -3.0e38f;
    srow[t] = 0.f;
  }

  f4v acc2[2][2];
#pragma unroll
  for (int i = 0; i < 2; ++i)
#pragma unroll
    for (int j = 0; j < 2; ++j) acc2[i][j] = {0.f, 0.f, 0.f, 0.f};

  for (int kc = 0; kc < 4; ++kc) {
    f4v acc[4][4];
#pragma unroll
    for (int i = 0; i < 4; ++i)
#pragma unroll
      for (int j = 0; j < 4; ++j) acc[i][j] = {0.f, 0.f, 0.f, 0.f};

#pragma unroll
    for (int khalf = 0; khalf < 2; ++khalf) {
      __syncthreads();
#pragma unroll
      for (int i = 0; i < 2; ++i) {
        const int g = w * 2 + i;
        gld_lds16(k + kvbase +
                      (long long)(kc * 256 + g * 16 + brow_l) * 64 +
                      khalf * 32 + bchunk,
                  smK + g * 512 + lane * 8);
      }
      __syncthreads();
#pragma unroll
      for (int mi = 0; mi < 4; ++mi) {
        const bf8v a0 =
            *(const bf8v*)&smQ[khalf * 4096 + (wr + mi * 16 + fr) * 32 + fco];
#pragma unroll
        for (int nj = 0; nj < 4; ++nj) {
          const bf8v b0 = *(const bf8v*)&smK[(wc + nj * 16 + fr) * 32 + fco];
          acc[mi][nj] =
              __builtin_amdgcn_mfma_f32_16x16x32_bf16(a0, b0, acc[mi][nj], 0, 0, 0);
        }
      }
    }
    __syncthreads();

#pragma unroll
    for (int mi = 0; mi < 4; ++mi)
#pragma unroll
      for (int j = 0; j < 4; ++j) {
        float m = fmaxf(fmaxf(acc[mi][0][j], acc[mi][1][j]),
                        fmaxf(acc[mi][2][j], acc[mi][3][j]));
#pragma unroll
        for (int o2 = 1; o2 < 16; o2 <<= 1) m = fmaxf(m, __shfl_xor(m, o2));
        if (fr == 0) partial[(w & 3) * 128 + wr + mi * 16 + fq * 4 + j] = m;
      }
    __syncthreads();
    if (t < 128) {
      const float cm = fmaxf(fmaxf(partial[t], partial[128 + t]),
                             fmaxf(partial[256 + t], partial[384 + t]));
      const float mnew = fmaxf(mold[t], cm);
      fbuf[t] = exp2f(mold[t] - mnew);
      mold[t] = mnew;
    }
    __syncthreads();

#pragma unroll
    for (int mi = 0; mi < 4; ++mi)
#pragma unroll
      for (int j = 0; j < 4; ++j) {
        const int row = wr + mi * 16 + fq * 4 + j;
        const float rm = mold[row];
        float s = 0.f;
#pragma unroll
        for (int nj = 0; nj < 4; ++nj) {
          const float e = exp2f(acc[mi][nj][j] - rm);
          s += e;
          const int col = wc + nj * 16 + fr;
          const int kc2 = col >> 5, kloc = col & 31;
          Pbuf[kc2 * 4096 + row * 32 + (((kloc >> 3) ^ ((row >> 1) & 3)) * 8) +
               (kloc & 7)] = bf16_rne(e);
        }
#pragma unroll
        for (int o2 = 1; o2 < 16; o2 <<= 1) s += __shfl_xor(s, o2);
        if (fr == 0) partial[(w & 3) * 128 + row] = s;
      }
    if (w < 4) {
      gld_lds16(vt + kvbase + (long long)(w * 16 + brow_l) * 1024 + kc * 256 +
                    bchunk,
                smV + w * 512 + lane * 8);
    }
    __syncthreads();
    if (t < 128)
      srow[t] = srow[t] * fbuf[t] +
                ((partial[t] + partial[128 + t]) +
                 (partial[256 + t] + partial[384 + t]));
    __syncthreads();

#pragma unroll
    for (int mi = 0; mi < 2; ++mi)
#pragma unroll
      for (int j = 0; j < 4; ++j) {
        const float fr_ = fbuf[wrp + mi * 16 + fq * 4 + j];
        acc2[mi][0][j] *= fr_;
        acc2[mi][1][j] *= fr_;
      }

    for (int sk = 0; sk < 8; ++sk) {
      const int cur = (sk & 1) * 2048;
      if (sk < 7 && w < 4) {
        gld_lds16(vt + kvbase + (long long)(w * 16 + brow_l) * 1024 +
                      kc * 256 + (sk + 1) * 32 + bchunk,
                  smV + (2048 - cur) + w * 512 + lane * 8);
      }
#pragma unroll
      for (int mi = 0; mi < 2; ++mi) {
        const bf8v pa =
            *(const bf8v*)&Pbuf[sk * 4096 + (wrp + mi * 16 + fr) * 32 + fco];
#pragma unroll
        for (int nj = 0; nj < 2; ++nj) {
          const bf8v v0 =
              *(const bf8v*)&smV[cur + (wcp + nj * 16 + fr) * 32 + fco];
          acc2[mi][nj] =
              __builtin_amdgcn_mfma_f32_16x16x32_bf16(pa, v0, acc2[mi][nj], 0, 0, 0);
        }
      }
      __syncthreads();
    }
  }

  if (t < 128) fbuf[t] = 1.f / srow[t];
  __syncthreads();
  const long long ooff = (long long)qrow0 * 768 + h * 64;
#pragma unroll
  for (int mi = 0; mi < 2; ++mi)
#pragma unroll
    for (int nj = 0; nj < 2; ++nj)
#pragma unroll
      for (int j = 0; j < 4; ++j) {
        const int row = wrp + mi * 16 + fq * 4 + j;
        const int col = wcp + nj * 16 + fr;
        o[ooff + (long long)row * 768 + col] =
            bf16_rne(acc2[mi][nj][j] * fbuf[row]);
      }
}

// ---------------- fused unpack attention (bf16, strided q/k) ----------------
__global__ __launch_bounds__(512) void fused_unpack_attn(
    const u16* __restrict__ q, int ldq, const u16* __restrict__ k, int ldk,
    const u16* __restrict__ vt, u16* __restrict__ o) {
  __shared__ char pool[76800];
  u16* smA = (u16*)pool;
  u16* smB = (u16*)(pool + 8192);
  u16* Pbuf = (u16*)pool;
  u16* smV = (u16*)(pool + 65536);
  float* partial = (float*)(pool + 73728);
  float* rowmax = (float*)(pool + 75776);
  float* rowsum = (float*)(pool + 76288);

  const int t = threadIdx.x;
  const int w = t >> 6, lane = t & 63;
  const int z = blockIdx.z;
  const int b = z / 12, h = z % 12;
  const int q0 = blockIdx.x * 128;

  const long long qoff = (long long)(b * 4096 + q0) * ldq + h * 64;
  const long long koff = (long long)(b * 256) * ldk + h * 64;
  const long long vbase = ((long long)(b * 12 + h)) * 16384;
  const long long ooff = (long long)(b * 4096 + q0) * 768 + h * 64;

  const int fr = lane & 15, fq = lane >> 4;
  const int fco = (fq ^ ((lane >> 1) & 3)) * 8;
  const int brow_l = lane >> 2;
  const int bchunk = ((lane & 3) ^ ((lane >> 3) & 3)) * 8;

  const int wr = (w >> 2) * 64, wc = (w & 3) * 64;
  f4v acc[4][4];
#pragma unroll
  for (int i = 0; i < 4; ++i)
#pragma unroll
    for (int j = 0; j < 4; ++j) acc[i][j] = {0.f, 0.f, 0.f, 0.f};

  for (int k0 = 0; k0 < 64; k0 += 32) {
    __syncthreads();
#pragma unroll
    for (int i = 0; i < 2; ++i) {
      const int g = w * 2 + i;
      const int r = g * 16 + brow_l;
      gld_lds16(k + koff + (long long)r * ldk + k0 + bchunk,
                smB + g * 512 + lane * 8);
    }
    {
      const int r = w * 16 + brow_l;
      gld_lds16(q + qoff + (long long)r * ldq + k0 + bchunk,
                smA + w * 512 + lane * 8);
    }
    __syncthreads();
#pragma unroll
    for (int mi = 0; mi < 4; ++mi) {
      const bf8v a0 = *(const bf8v*)&smA[(wr + mi * 16 + fr) * 32 + fco];
#pragma unroll
      for (int nj = 0; nj < 4; ++nj) {
        const bf8v b0 = *(const bf8v*)&smB[(wc + nj * 16 + fr) * 32 + fco];
        acc[mi][nj] = __builtin_amdgcn_mfma_f32_16x16x32_bf16(a0, b0, acc[mi][nj], 0, 0, 0);
      }
    }
  }
  __syncthreads();

  if (w < 4) {
    const int r = w * 16 + brow_l;
    gld_lds16(vt + vbase + (long long)r * 256 + bchunk,
              smV + w * 512 + lane * 8);
  }

#pragma unroll
  for (int mi = 0; mi < 4; ++mi)
#pragma unroll
    for (int j = 0; j < 4; ++j) {
      float m = fmaxf(fmaxf(acc[mi][0][j], acc[mi][1][j]),
                      fmaxf(acc[mi][2][j], acc[mi][3][j]));
#pragma unroll
      for (int o2 = 1; o2 < 16; o2 <<= 1) m = fmaxf(m, __shfl_xor(m, o2));
      if (fr == 0) partial[(w & 3) * 128 + wr + mi * 16 + fq * 4 + j] = m;
    }
  __syncthreads();
  if (t < 128)
    rowmax[t] = fmaxf(fmaxf(partial[t], partial[128 + t]),
                      fmaxf(partial[256 + t], partial[384 + t]));
  __syncthreads();
#pragma unroll
  for (int mi = 0; mi < 4; ++mi)
#pragma unroll
    for (int j = 0; j < 4; ++j) {
      const int row = wr + mi * 16 + fq * 4 + j;
      const float rm = rowmax[row];
      float s = 0.f;
#pragma unroll
      for (int nj = 0; nj < 4; ++nj) {
        const float e = exp2f(acc[mi][nj][j] - rm);
        s += e;
        const int col = wc + nj * 16 + fr;
        const int kc = col >> 5, kloc = col & 31;
        Pbuf[kc * 4096 + row * 32 + (((kloc >> 3) ^ ((row >> 1) & 3)) * 8) +
             (kloc & 7)] = bf16_rne(e);
      }
#pragma unroll
      for (int o2 = 1; o2 < 16; o2 <<= 1) s += __shfl_xor(s, o2);
      if (fr == 0) partial[(w & 3) * 128 + row] = s;
    }
  __syncthreads();
  if (t < 128)
    rowsum[t] = 1.f / ((partial[t] + partial[128 + t]) +
                       (partial[256 + t] + partial[384 + t]));
  __syncthreads();

  const int wrp = (w >> 1) * 32, wcp = (w & 1) * 32;
  f4v acc2[2][2];
#pragma unroll
  for (int i = 0; i < 2; ++i)
#pragma unroll
    for (int j = 0; j < 2; ++j) acc2[i][j] = {0.f, 0.f, 0.f, 0.f};

  for (int kc = 0; kc < 8; ++kc) {
    const int cur = (kc & 1) * 2048;
    if (kc < 7 && w < 4) {
      const int r = w * 16 + brow_l;
      gld_lds16(vt + vbase + (long long)r * 256 + (kc + 1) * 32 + bchunk,
                smV + (2048 - cur) + w * 512 + lane * 8);
    }
#pragma unroll
    for (int mi = 0; mi < 2; ++mi) {
      const bf8v pa =
          *(const bf8v*)&Pbuf[kc * 4096 + (wrp + mi * 16 + fr) * 32 + fco];
#pragma unroll
      for (int nj = 0; nj < 2; ++nj) {
        const bf8v v0 =
            *(const bf8v*)&smV[cur + (wcp + nj * 16 + fr) * 32 + fco];
        acc2[mi][nj] = __builtin_amdgcn_mfma_f32_16x16x32_bf16(pa, v0, acc2[mi][nj], 0, 0, 0);
      }
    }
    __syncthreads();
  }
#pragma unroll
  for (int mi = 0; mi < 2; ++mi)
#pragma unroll
    for (int nj = 0; nj < 2; ++nj)
#pragma unroll
      for (int j = 0; j < 4; ++j) {
        const int row = wrp + mi * 16 + fq * 4 + j;
        const int col = wcp + nj * 16 + fr;
        o[ooff + (long long)row * 768 + col] =
            bf16_rne(acc2[mi][nj][j] * rowsum[row]);
      }
}

// ---------------- dual conv pool (bf16 in): k -> [b,h,t,dh], v -> [b,h,dh,t]
__global__ __launch_bounds__(256) void conv_dual_kernel(
    const u16* __restrict__ in, const float* __restrict__ w,
    u16* __restrict__ ok, u16* __restrict__ ovT, int total, int ld) {
  int idx = blockIdx.x * 256 + threadIdx.x;
  if (idx >= total) return;
  const int dh = idx & 63;
  int r = idx >> 6;
  const int tt = r & 1023; r >>= 10;
  const int h = r % 12;
  const int b = r / 12;
  const long long s = ((long long)(b * 4096 + 4 * tt)) * ld + h * 64 + dh;
  const float* wh = w + h * 4;
  float vk = 0.f, vv = 0.f;
#pragma unroll
  for (int j = 0; j < 4; ++j) {
    vk = fmaf(wh[j], bf16_to_f(in[s + j * ld]), vk);
    vv = fmaf(wh[j], bf16_to_f(in[s + 768 + j * ld]), vv);
  }
  ok[idx] = bf16_rne(vk);
  ovT[(((long long)(b * 12 + h)) * 64 + dh) * 1024 + tt] = bf16_rne(vv);
}

// ---------------- transpose: bf16 [4,256,ld] col-slice -> [b,h,dh,key] ------
__global__ __launch_bounds__(256) void transT_b2b_kernel(
    const u16* __restrict__ in, u16* __restrict__ o, int total, int ld) {
  int idx = blockIdx.x * 256 + threadIdx.x;
  if (idx >= total) return;
  const int key = idx & 255;
  int r = idx >> 8;
  const int dh = r & 63; r >>= 6;
  const int h = r % 12;
  const int b = r / 12;
  o[idx] = in[((long long)(b * 256 + key)) * ld + h * 64 + dh];
}

// ---------------- LayerNorm(a + b*maskf), b fp32 OR bf16 --------------------
template <int BBF16>
__global__ __launch_bounds__(256) void ln_kernel(
    const float* __restrict__ a, const float* __restrict__ bf,
    const u16* __restrict__ bb, const int* __restrict__ mask,
    float* __restrict__ out, u16* __restrict__ outb) {
  const long long row = blockIdx.x;
  const float* pa = a + row * 768;
  const float ms = mask ? (float)mask[row] : 1.f;
  __shared__ float buf[768];
  __shared__ float red[4];
  const int t = threadIdx.x;
  float lsum = 0.f;
#pragma unroll
  for (int i = t; i < 768; i += 256) {
    const float bvv = BBF16 ? bf16_to_f(bb[row * 768 + i]) : bf[row * 768 + i];
    const float v = fmaf(bvv, ms, pa[i]);
    buf[i] = v;
    lsum += v;
  }
  for (int o = 32; o; o >>= 1) lsum += __shfl_xor(lsum, o);
  if ((t & 63) == 0) red[t >> 6] = lsum;
  __syncthreads();
  const float mu = (red[0] + red[1] + red[2] + red[3]) * (1.f / 768.f);
  float lvar = 0.f;
#pragma unroll
  for (int i = t; i < 768; i += 256) {
    const float d = buf[i] - mu;
    lvar = fmaf(d, d, lvar);
  }
  __syncthreads();
  for (int o = 32; o; o >>= 1) lvar += __shfl_xor(lvar, o);
  if ((t & 63) == 0) red[t >> 6] = lvar;
  __syncthreads();
  const float var = (red[0] + red[1] + red[2] + red[3]) * (1.f / 768.f);
  const float rstd = rsqrtf(var + 1e-6f);
  float* po = out + row * 768;
  u16* pob = outb ? outb + row * 768 : nullptr;
#pragma unroll
  for (int i = t; i < 768; i += 256) {
    const float v = (buf[i] - mu) * rstd;
    po[i] = v;
    if (outb) pob[i] = bf16_rne(v);
  }
}

// ---------------- host ----------------
extern "C" void kernel_launch(void* const* d_in, const int* in_sizes, int n_in,
                              void* d_out, int out_size, void* d_ws,
                              size_t ws_size, hipStream_t stream) {
  const float* x = (const float*)d_in[0];
  const float* memory = (const float*)d_in[1];
  const int* mask = (const int*)d_in[2];
  const float* Wq = (const float*)d_in[3];
  const float* Wk = (const float*)d_in[4];
  const float* Wv = (const float*)d_in[5];
  const float* Wo = (const float*)d_in[6];
  const float* conv_w = (const float*)d_in[7];
  const float* Uq = (const float*)d_in[8];
  const float* Uk = (const float*)d_in[9];
  const float* Uv = (const float*)d_in[10];
  const float* Uo = (const float*)d_in[11];
  const float* W1 = (const float*)d_in[12];
  const float* W2 = (const float*)d_in[13];
  float* out = (float*)d_out;
  float* ws = (float*)d_ws;

  const int XR = 16384, MR = 1024, D = 768, MLP = 3072;
  const long long CB = 3145728;
  const int WD = 589824;
  const int WM = 2359296;

  float* A0 = ws + 0;         // 18.87M
  float* A1 = ws + 18874368;  // 12.58M
  float* A2 = ws + 31457280;  //  9.44M

  u16* xb    = (u16*)(A0 + 12582912);
  u16* kvqb  = (u16*)A0;
  u16* uattvb = (u16*)A1;
  u16* unpb  = (u16*)A0;
  float* qout1 = A0 + 6291456;
  u16* qout1b = (u16*)(out + 6291456);
  u16* hb    = (u16*)A1;
  float* ybuf = A2;

  u16* kpb  = (u16*)A2;
  u16* vpTb = kpb + 3145728;
  u16* qpb  = (u16*)(A2 + 3145728);
  u16* memb = qpb + 786432;
  u16* avmb = (u16*)(A2 + 3932160);
  u16* pkb  = avmb + 786432;
  float* packed = A2 + 4718592;
  u16* ukvb = (u16*)(A2 + 5505024);
  u16* uvTb = (u16*)(A2 + 6291456);
  u16* wp16 = (u16*)(A2 + 7077888);

  u16* Wkvqb = wp16;                      // [2304][768]
  u16* Wqb = wp16 + 2304 * 768;
  u16* Wob = Wqb + WD;
  u16* Ukvb2 = wp16;                      // [1536][768]
  u16* Uob = wp16 + 1536 * 768;
  u16* W1b = wp16;
  u16* W2b = wp16 + WM;

  const float UQS = 0.18033688011112042592f;  // 1/8 * log2(e)
  const float L2E = 1.4426950408889634074f;   // log2(e)

  // ---- pack phase: batched conversions ----
  {
    Cvt8 c{};
    const float* ss[7] = {x, memory, Wk, Wv, Uq, Wq, Wo};
    u16* dd[7] = {xb, memb, Wkvqb, Wkvqb + WD, Wkvqb + 2 * WD, Wqb, Wob};
    int nn[7] = {3145728, 196608, WD / 4, WD / 4, WD / 4, WD / 4, WD / 4};
    float sc[7] = {1.f, 1.f, 1.f, 1.f, UQS, 1.f, 1.f};
    int cum = 0;
    for (int i = 0; i < 7; ++i) {
      c.src[i] = ss[i]; c.dst[i] = dd[i]; c.n4[i] = nn[i]; c.sc[i] = sc[i];
      c.cum[i] = cum; cum += (nn[i] + 255) / 256;
    }
    c.cum[7] = cum; c.ns = 7;
    tobf16_multi_kernel<<<cum, 256, 0, stream>>>(c);
  }
  // merged kvq projection (BM=256, 512 thr, 8 waves)
  bgemm_kernel<256, 128, 0, 1><<<dim3(18, 64, 1), 512, 0, stream>>>(
      xb, Wkvqb, nullptr, kvqb, XR, 2304, D, D, D, 2304,
      0, 0, 0, 0, 0, 0, 1, 1.f);
  bgemm_kernel<128, 128, 0, 1><<<dim3(6, 8, 1), 256, 0, stream>>>(
      memb, Wqb, nullptr, qpb, MR, D, D, D, D, D, 0, 0, 0, 0, 0, 0, 1, L2E);
  conv_dual_kernel<<<12288, 256, 0, stream>>>(kvqb, conv_w, kpb, vpTb,
                                              3145728, 2304);
  {
    dim3 g(2, 1, 48);
    fused_pack_attn<<<g, 512, 0, stream>>>(qpb, kpb, vpTb, avmb);
  }
  bgemm_kernel<128, 128, 0, 2><<<dim3(6, 8, 1), 256, 0, stream>>>(
      avmb, Wob, packed, pkb, MR, D, D, D, D, D, 0, 0, 0, 0, 0, 0, 1, 1.f);
  ln_kernel<0><<<MR, 256, 0, stream>>>(memory, packed, nullptr, nullptr,
                                       out + 12582912, nullptr);

  // ---- unpack phase ----
  {
    Cvt8 c{};
    const float* ss[3] = {Uk, Uv, Uo};
    u16* dd[3] = {Ukvb2, Ukvb2 + WD, Uob};
    int cum = 0;
    for (int i = 0; i < 3; ++i) {
      c.src[i] = ss[i]; c.dst[i] = dd[i]; c.n4[i] = WD / 4; c.sc[i] = 1.f;
      c.cum[i] = cum; cum += (WD / 4 + 255) / 256;
    }
    c.cum[3] = cum; c.ns = 3;
    tobf16_multi_kernel<<<cum, 256, 0, stream>>>(c);
  }
  bgemm_kernel<128, 128, 0, 1><<<dim3(12, 8, 1), 256, 0, stream>>>(
      pkb, Ukvb2, nullptr, ukvb, MR, 1536, D, D, D, 1536,
      0, 0, 0, 0, 0, 0, 1, 1.f);
  transT_b2b_kernel<<<3072, 256, 0, stream>>>(ukvb + 768, uvTb, 786432, 1536);
  {
    dim3 g(32, 1, 48);
    fused_unpack_attn<<<g, 512, 0, stream>>>(kvqb + 1536, 2304, ukvb, 1536,
                                             uvTb, uattvb);
  }
  // Uo (BM=256, z=4) -> unpb bf16; LN -> qout1 fp32 + bf16
  bgemm_kernel<256, 128, 0, 1><<<dim3(6, 16, 4), 512, 0, stream>>>(
      uattvb, Uob, nullptr, unpb, 4096, D, D, D, D, D,
      CB, 0, 0, 0, CB, 0, 1, 1.f);
  ln_kernel<1><<<XR, 256, 0, stream>>>(x, nullptr, unpb, mask, qout1, qout1b);

  // ---- FFN phase ----
  {
    Cvt8 c{};
    const float* ss[2] = {W1, W2};
    u16* dd[2] = {W1b, W2b};
    int cum = 0;
    for (int i = 0; i < 2; ++i) {
      c.src[i] = ss[i]; c.dst[i] = dd[i]; c.n4[i] = WM / 4; c.sc[i] = 1.f;
      c.cum[i] = cum; cum += (WM / 4 + 255) / 256;
    }
    c.cum[2] = cum; c.ns = 2;
    tobf16_multi_kernel<<<cum, 256, 0, stream>>>(c);
  }
  for (int c = 0; c < 2; ++c) {
    // W1+GELU (BM=256)
    bgemm_kernel<256, 128, 1, 1><<<dim3(24, 16, 2), 512, 0, stream>>>(
        qout1b + (long long)c * 2 * CB, W1b, nullptr, hb, 4096, MLP, D,
        D, D, MLP, CB, 0, 0, 0, 12582912, 0, 1, 1.f);
    // W2 (BM=128)
    bgemm_kernel<128, 128, 0, 0><<<dim3(6, 32, 2), 256, 0, stream>>>(
        hb, W2b, ybuf, nullptr, 4096, D, MLP, MLP, MLP, D,
        12582912, 0, 0, 0, CB, 0, 1, 1.f);
    ln_kernel<0><<<8192, 256, 0, stream>>>(qout1 + (long long)c * 2 * CB, ybuf,
                                           nullptr, mask + c * 8192,
                                           out + (long long)c * 2 * CB, nullptr);
  }
}